// Round 8
// baseline (384.350 us; speedup 1.0000x reference)
//
#include <hip/hip_runtime.h>
#include <hip/hip_bf16.h>
#include <math.h>

#define T_SEQ 2048
#define QSTR  3648   // combined q|qrot|krot|dkv row stride

typedef __bf16 bf16x8 __attribute__((ext_vector_type(8)));
typedef float  f32x4  __attribute__((ext_vector_type(4)));
typedef unsigned int u32x4 __attribute__((ext_vector_type(4)));

#define GLOAD_LDS16(g, l) __builtin_amdgcn_global_load_lds( \
    (const __attribute__((address_space(1))) void*)(g),      \
    (__attribute__((address_space(3))) void*)(l), 16, 0, 0)

#define VMCNT(n) asm volatile("s_waitcnt vmcnt(" #n ")" ::: "memory")

static __device__ __forceinline__ unsigned cvtpk_bf16(float a, float b)
{
    unsigned r;
    asm("v_cvt_pk_bf16_f32 %0, %1, %2" : "=v"(r) : "v"(a), "v"(b));
    return r;
}

// ---------------- fused fp32 -> bf16 cast for all 7 buffers ----------------
struct CastArgs {
    const float* s[7];
    __bf16*      d[7];
    unsigned     cum[8];    // cumulative block counts (2048 elements per block)
};

__global__ __launch_bounds__(256) void cast_all(CastArgs a)
{
    const unsigned blk = blockIdx.x;
    int idx = 0;
    #pragma unroll
    for (int i = 1; i < 7; i++) if (blk >= a.cum[i]) idx = i;
    const unsigned local = blk - a.cum[idx];
    const float* src = a.s[idx];
    __bf16* dst = a.d[idx];
    const int i = (int)(local * 256 + threadIdx.x) * 8;
    float4 va = *reinterpret_cast<const float4*>(src + i);
    float4 vb = *reinterpret_cast<const float4*>(src + i + 4);
    bf16x8 f;
    f[0] = (__bf16)va.x; f[1] = (__bf16)va.y; f[2] = (__bf16)va.z; f[3] = (__bf16)va.w;
    f[4] = (__bf16)vb.x; f[5] = (__bf16)vb.y; f[6] = (__bf16)vb.z; f[7] = (__bf16)vb.w;
    *reinterpret_cast<bf16x8*>(dst + i) = f;
}

// ---------------- in-place RoPE over 64-el head blocks (strided rows) -------
__global__ __launch_bounds__(256) void rope_ip(__bf16* buf, int shift, int stride,
                                               int total)
{
    int gid = blockIdx.x * 256 + threadIdx.x;
    if (gid >= total) return;
    int row = gid >> shift;
    int rem = gid & ((1 << shift) - 1);
    int hb = rem >> 5, j = rem & 31;
    int t = row & (T_SEQ - 1);
    const float L2B = 0.4152410118609203f;      // log2(10000)/32
    float freq = exp2f(-L2B * (float)j);
    float sn, cs;
    __sincosf((float)t * freq, &sn, &cs);
    size_t base = (size_t)row * stride + hb * 64 + j;
    float v1 = (float)buf[base], v2 = (float)buf[base + 32];
    buf[base]      = (__bf16)(v1 * cs - v2 * sn);
    buf[base + 32] = (__bf16)(v2 * cs + v1 * sn);
}

// ---------------- V pre-transpose: vtt[bh][u][dv(128)][k(64)] XOR-swizzled ---
__global__ __launch_bounds__(256) void prep_v(const __bf16* __restrict__ ukv,
                                              __bf16* __restrict__ vtt)
{
    __shared__ __align__(16) __bf16 Ls[64 * 136];
    const int tid = threadIdx.x;
    const int u = blockIdx.x, bh = blockIdx.y;
    const int b = bh >> 4, h = bh & 15;
    const size_t base = (size_t)b * T_SEQ + u * 64;
    #pragma unroll
    for (int p = 0; p < 4; p++) {
        int c = tid + 256 * p;
        int k = c >> 4, dv8 = (c & 15) * 8;
        *reinterpret_cast<bf16x8*>(Ls + k * 136 + dv8) =
            *reinterpret_cast<const bf16x8*>(ukv + (base + k) * 4096 + h * 256 + 128 + dv8);
    }
    __syncthreads();
    #pragma unroll
    for (int p = 0; p < 4; p++) {
        int c = tid + 256 * p;
        int dv = c >> 3, kb = c & 7;
        bf16x8 f;
        #pragma unroll
        for (int i = 0; i < 8; i++) f[i] = Ls[(kb * 8 + i) * 136 + dv];
        *reinterpret_cast<bf16x8*>(vtt + (((size_t)bh * 32 + u) * 128 + dv) * 64
                                   + ((kb ^ (dv & 7)) << 3)) = f;
    }
}

// ---------------- 256x256 snake-phase counted-vmcnt GEMM --------------------
template <typename OutT>
__global__ __launch_bounds__(512, 2) void gemm_bt_256(const __bf16* __restrict__ A,
                                                      int lda,
                                                      const __bf16* __restrict__ B,
                                                      OutT* __restrict__ C,
                                                      int M, int N, int K)
{
    __shared__ __align__(16) __bf16 S[2 * 32768];   // 128KB
    const int tid  = threadIdx.x;
    const int lane = tid & 63;
    const int w    = tid >> 6;
    const int l15  = lane & 15, quad = lane >> 4;
    const int wm = w >> 2, wn = w & 3;
    const int m0 = blockIdx.y * 256, n0 = blockIdx.x * 256;
    const int NT = K >> 6;

    f32x4 acc[8][4] = {};
    bf16x8 af[4][2], bfr[2][2];

    auto stageA = [&](int T1, int h) {
        int d = T1 & 1;
        #pragma unroll
        for (int i = 0; i < 2; i++) {
            int c = i * 512 + tid;
            int lr = c >> 3, seg = c & 7;
            int g = ((lr >> 6) << 7) + h * 64 + (lr & 63);
            GLOAD_LDS16(A + (size_t)(m0 + g) * lda + T1 * 64 + ((seg ^ (lr & 7)) << 3),
                        S + d * 32768 + h * 8192 + c * 8);
        }
    };
    auto stageB = [&](int T1, int h) {
        int d = T1 & 1;
        #pragma unroll
        for (int i = 0; i < 2; i++) {
            int c = i * 512 + tid;
            int lr = c >> 3, seg = c & 7;
            int g = n0 + ((lr >> 5) << 6) + h * 32 + (lr & 31);
            if (g >= N) g = N - 1;
            GLOAD_LDS16(B + (size_t)g * K + T1 * 64 + ((seg ^ (lr & 7)) << 3),
                        S + d * 32768 + 16384 + h * 8192 + c * 8);
        }
    };

#define LOADA(d, mh) do {                                                      \
    const __bf16* Ah_ = S + (d) * 32768 + (mh) * 8192;                         \
    _Pragma("unroll")                                                          \
    for (int mi = 0; mi < 4; mi++) {                                           \
        int lr = wm * 64 + mi * 16 + l15;                                      \
        _Pragma("unroll")                                                      \
        for (int kk = 0; kk < 2; kk++)                                         \
            af[mi][kk] = *reinterpret_cast<const bf16x8*>(                     \
                Ah_ + lr * 64 + (((kk * 4 + quad) ^ (lr & 7)) << 3));          \
    }                                                                          \
} while (0)

#define LOADB(d, nh) do {                                                      \
    const __bf16* Bh_ = S + (d) * 32768 + 16384 + (nh) * 8192;                 \
    _Pragma("unroll")                                                          \
    for (int ni = 0; ni < 2; ni++) {                                           \
        int lr = wn * 32 + ni * 16 + l15;                                      \
        _Pragma("unroll")                                                      \
        for (int kk = 0; kk < 2; kk++)                                         \
            bfr[ni][kk] = *reinterpret_cast<const bf16x8*>(                    \
                Bh_ + lr * 64 + (((kk * 4 + quad) ^ (lr & 7)) << 3));          \
    }                                                                          \
} while (0)

#define SEAL() do {                                                            \
    __builtin_amdgcn_s_barrier();                                              \
    asm volatile("s_waitcnt lgkmcnt(0)" ::: "memory");                         \
    __builtin_amdgcn_sched_barrier(0);                                         \
} while (0)

#define MMA(mh, nh) do {                                                       \
    __builtin_amdgcn_s_setprio(1);                                             \
    _Pragma("unroll")                                                          \
    for (int mi = 0; mi < 4; mi++)                                             \
        _Pragma("unroll")                                                      \
        for (int ni = 0; ni < 2; ni++)                                         \
            _Pragma("unroll")                                                  \
            for (int kk = 0; kk < 2; kk++)                                     \
                acc[(mh) * 4 + mi][(nh) * 2 + ni] =                            \
                    __builtin_amdgcn_mfma_f32_16x16x32_bf16(                   \
                        af[mi][kk], bfr[ni][kk],                               \
                        acc[(mh) * 4 + mi][(nh) * 2 + ni], 0, 0, 0);           \
    __builtin_amdgcn_s_setprio(0);                                             \
} while (0)

    stageA(0, 0); stageB(0, 0); stageB(0, 1); stageA(0, 1);
    VMCNT(4);
    __builtin_amdgcn_s_barrier();

    for (int T = 0; T < NT - 1; T++) {
        const int d = T & 1;
        LOADA(d, 0); LOADB(d, 0); stageA(T + 1, 0); VMCNT(4); SEAL(); MMA(0, 0);
        LOADB(d, 1);              stageB(T + 1, 0); VMCNT(4); SEAL(); MMA(0, 1);
        LOADA(d, 1);              stageB(T + 1, 1);           SEAL(); MMA(1, 1);
        LOADB(d, 0);              stageA(T + 1, 1); VMCNT(4); SEAL(); MMA(1, 0);
    }
    {
        const int d = (NT - 1) & 1;
        LOADA(d, 0); LOADB(d, 0); VMCNT(2); SEAL(); MMA(0, 0);
        LOADB(d, 1);              VMCNT(0); SEAL(); MMA(0, 1);
        LOADA(d, 1);                        SEAL(); MMA(1, 1);
        LOADB(d, 0);                        SEAL(); MMA(1, 0);
    }
#undef LOADA
#undef LOADB
#undef SEAL
#undef MMA

    #pragma unroll
    for (int ai = 0; ai < 8; ai++) {
        #pragma unroll
        for (int bj = 0; bj < 4; bj++) {
            int col = n0 + wn * 64 + bj * 16 + l15;
            if (col < N) {
                #pragma unroll
                for (int r = 0; r < 4; r++) {
                    size_t row = m0 + wm * 128 + ai * 16 + quad * 4 + r;
                    C[row * (size_t)N + col] = (OutT)acc[ai][bj][r];
                }
            }
        }
    }
}

// ---------------- 8-phase counted-vmcnt GEMM, BM=128 (kept for out GEMM) ----
template <typename OutT>
__global__ __launch_bounds__(512) void gemm_bt_8ph(const __bf16* __restrict__ A,
                                                   int lda,
                                                   const __bf16* __restrict__ B,
                                                   OutT* __restrict__ C,
                                                   int M, int N, int K)
{
    __shared__ __align__(16) __bf16 S[2 * 24576];   // 96KB
    const int tid  = threadIdx.x;
    const int lane = tid & 63;
    const int w    = tid >> 6;
    const int l15  = lane & 15, quad = lane >> 4;
    const int wm = w >> 2, wn = w & 3;
    const int m0 = blockIdx.y * 128, n0 = blockIdx.x * 256;
    const int NT = K >> 6;

    f32x4 acc[4][4] = {};

    const int lrA = tid >> 3, segA = tid & 7;

    auto stageA = [&](int T1, int h) {
        int d = T1 & 1;
        int g = ((lrA >> 5) << 6) + h * 32 + (lrA & 31);
        GLOAD_LDS16(A + (size_t)(m0 + g) * lda + T1 * 64 + ((segA ^ (lrA & 7)) << 3),
                    S + d * 24576 + h * 4096 + tid * 8);
    };
    auto stageB = [&](int T1, int h) {
        int d = T1 & 1;
        #pragma unroll
        for (int i = 0; i < 2; i++) {
            int c = i * 512 + tid;
            int lr = c >> 3, seg = c & 7;
            int g = n0 + ((lr >> 5) << 6) + h * 32 + (lr & 31);
            if (g >= N) g = N - 1;
            GLOAD_LDS16(B + (size_t)g * K + T1 * 64 + ((seg ^ (lr & 7)) << 3),
                        S + d * 24576 + 8192 + h * 8192 + c * 8);
        }
    };

#define PHASE(d, mh, nh, STAGE, WAIT) do {                                     \
    const __bf16* Ah_ = S + (d) * 24576 + (mh) * 4096;                         \
    const __bf16* Bh_ = S + (d) * 24576 + 8192 + (nh) * 8192;                  \
    bf16x8 af[2][2], bfr[2][2];                                                \
    _Pragma("unroll")                                                          \
    for (int mr = 0; mr < 2; mr++) {                                           \
        int ar = wm * 32 + mr * 16 + l15;                                      \
        _Pragma("unroll")                                                      \
        for (int kk = 0; kk < 2; kk++)                                         \
            af[mr][kk] = *reinterpret_cast<const bf16x8*>(                     \
                Ah_ + ar * 64 + (((kk * 4 + quad) ^ (ar & 7)) << 3));          \
    }                                                                          \
    _Pragma("unroll")                                                          \
    for (int nr = 0; nr < 2; nr++) {                                           \
        int br = wn * 32 + nr * 16 + l15;                                      \
        _Pragma("unroll")                                                      \
        for (int kk = 0; kk < 2; kk++)                                         \
            bfr[nr][kk] = *reinterpret_cast<const bf16x8*>(                    \
                Bh_ + br * 64 + (((kk * 4 + quad) ^ (br & 7)) << 3));          \
    }                                                                          \
    STAGE;                                                                     \
    WAIT;                                                                      \
    __builtin_amdgcn_s_barrier();                                              \
    asm volatile("s_waitcnt lgkmcnt(0)" ::: "memory");                         \
    __builtin_amdgcn_sched_barrier(0);                                         \
    __builtin_amdgcn_s_setprio(1);                                             \
    _Pragma("unroll")                                                          \
    for (int mr = 0; mr < 2; mr++)                                             \
        _Pragma("unroll")                                                      \
        for (int nr = 0; nr < 2; nr++)                                         \
            _Pragma("unroll")                                                  \
            for (int kk = 0; kk < 2; kk++)                                     \
                acc[(mh) * 2 + mr][(nh) * 2 + nr] =                            \
                    __builtin_amdgcn_mfma_f32_16x16x32_bf16(                   \
                        af[mr][kk], bfr[nr][kk],                               \
                        acc[(mh) * 2 + mr][(nh) * 2 + nr], 0, 0, 0);           \
    __builtin_amdgcn_s_setprio(0);                                             \
} while (0)

    stageA(0, 0);
    stageB(0, 0);
    stageB(0, 1);
    stageA(0, 1);
    VMCNT(3);
    __builtin_amdgcn_s_barrier();

    for (int T = 0; T < NT - 1; T++) {
        const int d = T & 1;
        PHASE(d, 0, 0, stageA(T + 1, 0), VMCNT(2));
        PHASE(d, 0, 1, stageB(T + 1, 0), VMCNT(3));
        PHASE(d, 1, 0, stageB(T + 1, 1), (void)0);
        PHASE(d, 1, 1, stageA(T + 1, 1), VMCNT(3));
    }
    {
        const int d = (NT - 1) & 1;
        PHASE(d, 0, 0, (void)0, VMCNT(1));
        PHASE(d, 0, 1, (void)0, VMCNT(0));
        PHASE(d, 1, 0, (void)0, (void)0);
        PHASE(d, 1, 1, (void)0, (void)0);
    }
#undef PHASE

    #pragma unroll
    for (int ai = 0; ai < 4; ai++) {
        #pragma unroll
        for (int bj = 0; bj < 4; bj++) {
            int col = n0 + wn * 64 + bj * 16 + l15;
            if (col < N) {
                #pragma unroll
                for (int r = 0; r < 4; r++) {
                    size_t row = m0 + wm * 64 + ai * 16 + quad * 4 + r;
                    C[row * (size_t)N + col] = (OutT)acc[ai][bj][r];
                }
            }
        }
    }
}

// ---------------- MFMA flash attention v4: 16x16-swapped, 4 blocks/CU -------
// Grid (32,32) = 1024 blocks; 64-q tile, 4 waves x 16 q (lane&15 = q-col).
// Single-buffered 40KB LDS (KN 16K|KR 8K|VT 16K) -> 4 blocks/CU = 4 waves/SIMD;
// ~90 VGPR (qf 24 + o 32) fits the 128 cap of __launch_bounds__(256,4).
// S^T = mfma_16x16x32(K, Q): per lane 16 S-values (k = 16kt+4quad+r, q = l15);
// softmax in-lane + 2 quad shfl_xor; l deferred to epilogue. P^T B-frag for PV
// (k = quad*8+j, q = l15) gathered from source quads 2(quad&1)+{0,1} of tile
// 2ks+(quad>>1) via 8 cvt_pk + 16 shfl + 8 cndmask per unit. Staging drains
// vmcnt to 0 per unit; 4 blocks/CU of TLP hide the stall.
__global__ __launch_bounds__(256, 4) void flash_mfma(
    const __bf16* __restrict__ qcat, const __bf16* __restrict__ ukv,
    const __bf16* __restrict__ vtt, __bf16* __restrict__ obuf)
{
    __shared__ __align__(16) __bf16 LDS[20480];  // KN 8192 | KR 4096 | VT 8192 els

    const int tid  = threadIdx.x;
    const int w    = tid >> 6;
    const int lane = tid & 63;
    const int l15  = lane & 15;
    const int quad = lane >> 4;
    const int gx = blockIdx.x, gy = blockIdx.y;
    int bh, j;
    if (gy < 16) { bh = gy * 2;            j = gx; }          // anti-correlated
    else         { bh = (gy - 16) * 2 + 1; j = 31 - gx; }     // pair (j, 31-j)
    const int b = bh >> 4, h = bh & 15;
    const int q0 = j * 64;
    const float SCALE = 0.07216878364870323f;   // 1/sqrt(192)
    const size_t urow = (size_t)b * T_SEQ;

    __bf16* KN = LDS;
    __bf16* KR = LDS + 8192;
    __bf16* VT = LDS + 12288;

    // ---- Q fragments (B-operand: col = l15 = q, els dk = 32*dkc + 8*quad) ---
    const int q = q0 + 16 * w + l15;
    bf16x8 qf[6];
    {
        const __bf16* qrow = qcat + (urow + q) * QSTR + h * 128;
        #pragma unroll
        for (int dkc = 0; dkc < 4; dkc++)
            qf[dkc] = *reinterpret_cast<const bf16x8*>(qrow + 32 * dkc + 8 * quad);
        const __bf16* qrr = qcat + (urow + q) * QSTR + 2048 + h * 64;
        qf[4] = *reinterpret_cast<const bf16x8*>(qrr + 8 * quad);
        qf[5] = *reinterpret_cast<const bf16x8*>(qrr + 32 + 8 * quad);
    }

    f32x4 o[8] = {};                 // O^T: col q = l15, rows d = 16dt+4quad+r
    float m_i = -INFINITY, l_i = 0.f;
    const int key = l15 & 7;

    auto stage = [&](int u) {        // 10 global_load_lds per thread
        const size_t roff = urow + (size_t)64 * u;
        #pragma unroll
        for (int p = 0; p < 4; p++) {          // K-nope [64][128], swz source
            int c = tid + 256 * p;
            int row = c >> 4, seg = c & 15;
            GLOAD_LDS16(ukv + (roff + row) * 4096 + h * 256 + ((seg ^ (row & 7)) << 3),
                        KN + c * 8);
        }
        #pragma unroll
        for (int p = 0; p < 2; p++) {          // K-rope [64][64], swz source
            int c = tid + 256 * p;
            int row = c >> 3, seg = c & 7;
            GLOAD_LDS16(qcat + (roff + row) * QSTR + 3072 + ((seg ^ (row & 7)) << 3),
                        KR + c * 8);
        }
        const __bf16* vsrc = vtt + ((size_t)bh * 32 + u) * 8192;
        #pragma unroll
        for (int p = 0; p < 4; p++) {          // V^T flat copy (pre-swizzled)
            int c = tid + 256 * p;
            GLOAD_LDS16(vsrc + c * 8, VT + c * 8);
        }
    };

    const int nunits = j + 1;
    for (int u = 0; u < nunits; u++) {
        stage(u);
        VMCNT(0);
        __builtin_amdgcn_s_barrier();
        __builtin_amdgcn_sched_barrier(0);

        // ---- S^T = K Q^T : 4 k-tiles x (4 nope + 2 rope) MFMA ----
        f32x4 s[4] = {};
        __builtin_amdgcn_s_setprio(1);
        #pragma unroll
        for (int kt = 0; kt < 4; kt++) {
            const __bf16* kn = KN + (16 * kt + l15) * 128;
            const __bf16* kr = KR + (16 * kt + l15) * 64;
            #pragma unroll
            for (int dkc = 0; dkc < 4; dkc++) {
                bf16x8 kf = *reinterpret_cast<const bf16x8*>(
                    kn + (((4 * dkc + quad) ^ key) << 3));
                s[kt] = __builtin_amdgcn_mfma_f32_16x16x32_bf16(kf, qf[dkc], s[kt], 0, 0, 0);
            }
            #pragma unroll
            for (int dkc = 0; dkc < 2; dkc++) {
                bf16x8 kf = *reinterpret_cast<const bf16x8*>(
                    kr + (((4 * dkc + quad) ^ key) << 3));
                s[kt] = __builtin_amdgcn_mfma_f32_16x16x32_bf16(kf, qf[4 + dkc], s[kt], 0, 0, 0);
            }
        }
        __builtin_amdgcn_s_setprio(0);

        // ---- causal mask (last unit only) + in-lane softmax ----
        const bool domask = (u + 1 == nunits);
        const int k0 = 64 * u;
        float rmax = -INFINITY;
        #pragma unroll
        for (int kt = 0; kt < 4; kt++)
            #pragma unroll
            for (int r = 0; r < 4; r++) {
                float v = s[kt][r] * SCALE;
                if (domask && (k0 + 16 * kt + 4 * quad + r > q)) v = -INFINITY;
                s[kt][r] = v;
                rmax = fmaxf(rmax, v);
            }
        rmax = fmaxf(rmax, __shfl_xor(rmax, 16, 64));
        rmax = fmaxf(rmax, __shfl_xor(rmax, 32, 64));
        const float mnew  = fmaxf(m_i, rmax);
        const float alpha = __expf(m_i - mnew);
        m_i = mnew;
        float part = 0.f;
        #pragma unroll
        for (int kt = 0; kt < 4; kt++)
            #pragma unroll
            for (int r = 0; r < 4; r++) {
                float pv = __expf(s[kt][r] - mnew);
                s[kt][r] = pv;
                part += pv;
            }
        l_i = l_i * alpha + part;        // per-lane partial; quad-reduced at end
        #pragma unroll
        for (int dt = 0; dt < 8; dt++) o[dt] *= alpha;

        // ---- assemble P^T B-frags (k = quad*8+j) and PV ----
        __builtin_amdgcn_s_setprio(1);
        const int hi = quad >> 1;
        const int sA = 32 * (quad & 1) + l15;    // lane of source quad 2(quad&1)
        const int sB = sA + 16;                  // lane of source quad 2(quad&1)+1
        #pragma unroll
        for (int ks = 0; ks < 2; ks++) {
            unsigned x0 = cvtpk_bf16(s[2 * ks][0], s[2 * ks][1]);
            unsigned x1 = cvtpk_bf16(s[2 * ks][2], s[2 * ks][3]);
            unsigned y0 = cvtpk_bf16(s[2 * ks + 1][0], s[2 * ks + 1][1]);
            unsigned y1 = cvtpk_bf16(s[2 * ks + 1][2], s[2 * ks + 1][3]);
            unsigned u0x = __shfl(x0, sA, 64), u0y = __shfl(y0, sA, 64);
            unsigned u1x = __shfl(x1, sA, 64), u1y = __shfl(y1, sA, 64);
            unsigned u2x = __shfl(x0, sB, 64), u2y = __shfl(y0, sB, 64);
            unsigned u3x = __shfl(x1, sB, 64), u3y = __shfl(y1, sB, 64);
            u32x4 uv;
            uv[0] = hi ? u0y : u0x;
            uv[1] = hi ? u1y : u1x;
            uv[2] = hi ? u2y : u2x;
            uv[3] = hi ? u3y : u3x;
            bf16x8 pf = __builtin_bit_cast(bf16x8, uv);
            #pragma unroll
            for (int dt = 0; dt < 8; dt++) {
                bf16x8 vf = *reinterpret_cast<const bf16x8*>(
                    VT + (16 * dt + l15) * 64 + (((4 * ks + quad) ^ key) << 3));
                o[dt] = __builtin_amdgcn_mfma_f32_16x16x32_bf16(vf, pf, o[dt], 0, 0, 0);
            }
        }
        __builtin_amdgcn_s_setprio(0);

        __builtin_amdgcn_sched_barrier(0);
        __builtin_amdgcn_s_barrier();    // seal all LDS reads before next stage
    }

    // ---- epilogue: quad-reduce l, transpose O^T through LDS, store ----
    l_i += __shfl_xor(l_i, 16, 64);
    l_i += __shfl_xor(l_i, 32, 64);
    const float linv = 1.0f / l_i;
    float* Os = reinterpret_cast<float*>(LDS);   // [64 q][132 d] = 33.8KB
    #pragma unroll
    for (int dt = 0; dt < 8; dt++)
        #pragma unroll
        for (int r = 0; r < 4; r++) {
            int d = 16 * dt + 4 * quad + r;
            Os[(16 * w + l15) * 132 + d] = o[dt][r] * linv;
        }
    asm volatile("s_waitcnt lgkmcnt(0)" ::: "memory");
    __builtin_amdgcn_sched_barrier(0);
    // rows [16w,16w+16) written and read by wave w only: no cross-wave barrier
    #pragma unroll
    for (int p = 0; p < 4; p++) {
        int row = 16 * w + 4 * p + quad;
        float4 a4 = *reinterpret_cast<const float4*>(Os + row * 132 + 8 * l15);
        float4 c2 = *reinterpret_cast<const float4*>(Os + row * 132 + 8 * l15 + 4);
        bf16x8 f;
        f[0] = (__bf16)a4.x; f[1] = (__bf16)a4.y; f[2] = (__bf16)a4.z; f[3] = (__bf16)a4.w;
        f[4] = (__bf16)c2.x; f[5] = (__bf16)c2.y; f[6] = (__bf16)c2.z; f[7] = (__bf16)c2.w;
        *reinterpret_cast<bf16x8*>(obuf + (urow + q0 + row) * 2048 + h * 128 + 8 * l15) = f;
    }
}

extern "C" void kernel_launch(void* const* d_in, const int* in_sizes, int n_in,
                              void* d_out, int out_size, void* d_ws, size_t ws_size,
                              hipStream_t stream)
{
    const float* x      = (const float*)d_in[0];
    const float* w_q    = (const float*)d_in[1];
    const float* w_dkv  = (const float*)d_in[2];
    const float* w_ukv  = (const float*)d_in[3];
    const float* w_o    = (const float*)d_in[4];
    const float* w_qrot = (const float*)d_in[5];
    const float* w_krot = (const float*)d_in[6];
    float* out = (float*)d_out;

    const size_t M = 4096;
    __bf16* ws   = (__bf16*)d_ws;
    __bf16* xb   = ws;                        // 4096x2048
    __bf16* wcat = xb + M * 2048;             // 3648x2048 = [w_q|w_qrot|w_krot|w_dkv]
    __bf16* wqb  = wcat;
    __bf16* wqrb = wcat + (size_t)2048 * 2048;
    __bf16* wkrb = wqrb + (size_t)1024 * 2048;
    __bf16* wdkb = wkrb + (size_t)64 * 2048;
    __bf16* wukb = wcat + (size_t)QSTR * 2048; // 4096x512
    __bf16* wob  = wukb + (size_t)4096 * 512;  // 2048x2048
    __bf16* qcat = wob  + (size_t)2048 * 2048; // 4096x3648 (q|qrot|krot|dkv)
    __bf16* ukv  = qcat + M * QSTR;            // 4096x4096
    __bf16* ao   = ukv  + M * 4096;            // 4096x2048
    __bf16* vtt  = ao   + M * 2048;            // 1024 tiles x 128x64 (~16.8MB)

    dim3 blk(256);

    CastArgs ca;
    ca.s[0] = x;      ca.d[0] = xb;
    ca.s[1] = w_q;    ca.d[1] = wqb;
    ca.s[2] = w_qrot; ca.d[2] = wqrb;
    ca.s[3] = w_krot; ca.d[3] = wkrb;
    ca.s[4] = w_dkv;  ca.d[4] = wdkb;
    ca.s[5] = w_ukv;  ca.d[5] = wukb;
    ca.s[6] = w_o;    ca.d[6] = wob;
    ca.cum[0] = 0;
    ca.cum[1] = ca.cum[0] + 4096;
    ca.cum[2] = ca.cum[1] + 2048;
    ca.cum[3] = ca.cum[2] + 1024;
    ca.cum[4] = ca.cum[3] + 64;
    ca.cum[5] = ca.cum[4] + 512;
    ca.cum[6] = ca.cum[5] + 1024;
    ca.cum[7] = ca.cum[6] + 2048;
    cast_all<<<ca.cum[7], blk, 0, stream>>>(ca);

    gemm_bt_256<__bf16><<<dim3(15, 16), dim3(512), 0, stream>>>(
        xb, 2048, wcat, qcat, 4096, QSTR, 2048);
    gemm_bt_256<__bf16><<<dim3(16, 16), dim3(512), 0, stream>>>(
        qcat + 3136, QSTR, wukb, ukv, 4096, 4096, 512);

    rope_ip<<<8192, blk, 0, stream>>>(qcat + 2048, 9, QSTR, 4096 * 512);
    rope_ip<<<512,  blk, 0, stream>>>(qcat + 3072, 5, QSTR, 4096 * 32);
    prep_v<<<dim3(32, 32), blk, 0, stream>>>(ukv, vtt);

    flash_mfma<<<dim3(32, 32), blk, 0, stream>>>(qcat, ukv, vtt, ao);

    gemm_bt_8ph<float><<<dim3(8, 32), dim3(512), 0, stream>>>(
        ao, 2048, wob, out, 4096, 2048, 2048);
}

// Round 9
// 364.545 us; speedup vs baseline: 1.0543x; 1.0543x over previous
//
#include <hip/hip_runtime.h>
#include <hip/hip_bf16.h>
#include <math.h>

#define T_SEQ 2048
#define QSTR  3648   // combined q|qrot|krot|dkv row stride

typedef __bf16 bf16x8 __attribute__((ext_vector_type(8)));
typedef float  f32x4  __attribute__((ext_vector_type(4)));
typedef float  f32x16 __attribute__((ext_vector_type(16)));
typedef unsigned int u32x4 __attribute__((ext_vector_type(4)));

#define GLOAD_LDS16(g, l) __builtin_amdgcn_global_load_lds( \
    (const __attribute__((address_space(1))) void*)(g),      \
    (__attribute__((address_space(3))) void*)(l), 16, 0, 0)

#define VMCNT(n) asm volatile("s_waitcnt vmcnt(" #n ")" ::: "memory")

static __device__ __forceinline__ unsigned cvtpk_bf16(float a, float b)
{
    unsigned r;
    asm("v_cvt_pk_bf16_f32 %0, %1, %2" : "=v"(r) : "v"(a), "v"(b));
    return r;
}

static __device__ __forceinline__ float fexp2(float x)
{
    float r;
    asm("v_exp_f32 %0, %1" : "=v"(r) : "v"(x));
    return r;
}

// ---------------- fused fp32 -> bf16 cast for all 7 buffers ----------------
struct CastArgs {
    const float* s[7];
    __bf16*      d[7];
    unsigned     cum[8];    // cumulative block counts (2048 elements per block)
};

__global__ __launch_bounds__(256) void cast_all(CastArgs a)
{
    const unsigned blk = blockIdx.x;
    int idx = 0;
    #pragma unroll
    for (int i = 1; i < 7; i++) if (blk >= a.cum[i]) idx = i;
    const unsigned local = blk - a.cum[idx];
    const float* src = a.s[idx];
    __bf16* dst = a.d[idx];
    const int i = (int)(local * 256 + threadIdx.x) * 8;
    float4 va = *reinterpret_cast<const float4*>(src + i);
    float4 vb = *reinterpret_cast<const float4*>(src + i + 4);
    bf16x8 f;
    f[0] = (__bf16)va.x; f[1] = (__bf16)va.y; f[2] = (__bf16)va.z; f[3] = (__bf16)va.w;
    f[4] = (__bf16)vb.x; f[5] = (__bf16)vb.y; f[6] = (__bf16)vb.z; f[7] = (__bf16)vb.w;
    *reinterpret_cast<bf16x8*>(dst + i) = f;
}

// ---------------- in-place RoPE over 64-el head blocks (strided rows) -------
__global__ __launch_bounds__(256) void rope_ip(__bf16* buf, int shift, int stride,
                                               int total)
{
    int gid = blockIdx.x * 256 + threadIdx.x;
    if (gid >= total) return;
    int row = gid >> shift;
    int rem = gid & ((1 << shift) - 1);
    int hb = rem >> 5, j = rem & 31;
    int t = row & (T_SEQ - 1);
    const float L2B = 0.4152410118609203f;      // log2(10000)/32
    float freq = exp2f(-L2B * (float)j);
    float sn, cs;
    __sincosf((float)t * freq, &sn, &cs);
    size_t base = (size_t)row * stride + hb * 64 + j;
    float v1 = (float)buf[base], v2 = (float)buf[base + 32];
    buf[base]      = (__bf16)(v1 * cs - v2 * sn);
    buf[base + 32] = (__bf16)(v2 * cs + v1 * sn);
}

// ---------------- V pre-transpose: vtt[bh][u][dv(128)][k(64)] XOR-swizzled ---
__global__ __launch_bounds__(256) void prep_v(const __bf16* __restrict__ ukv,
                                              __bf16* __restrict__ vtt)
{
    __shared__ __align__(16) __bf16 Ls[64 * 136];
    const int tid = threadIdx.x;
    const int u = blockIdx.x, bh = blockIdx.y;
    const int b = bh >> 4, h = bh & 15;
    const size_t base = (size_t)b * T_SEQ + u * 64;
    #pragma unroll
    for (int p = 0; p < 4; p++) {
        int c = tid + 256 * p;
        int k = c >> 4, dv8 = (c & 15) * 8;
        *reinterpret_cast<bf16x8*>(Ls + k * 136 + dv8) =
            *reinterpret_cast<const bf16x8*>(ukv + (base + k) * 4096 + h * 256 + 128 + dv8);
    }
    __syncthreads();
    #pragma unroll
    for (int p = 0; p < 4; p++) {
        int c = tid + 256 * p;
        int dv = c >> 3, kb = c & 7;
        bf16x8 f;
        #pragma unroll
        for (int i = 0; i < 8; i++) f[i] = Ls[(kb * 8 + i) * 136 + dv];
        *reinterpret_cast<bf16x8*>(vtt + (((size_t)bh * 32 + u) * 128 + dv) * 64
                                   + ((kb ^ (dv & 7)) << 3)) = f;
    }
}

// ---------------- 256x256 snake-phase counted-vmcnt GEMM --------------------
template <typename OutT>
__global__ __launch_bounds__(512, 2) void gemm_bt_256(const __bf16* __restrict__ A,
                                                      int lda,
                                                      const __bf16* __restrict__ B,
                                                      OutT* __restrict__ C,
                                                      int M, int N, int K)
{
    __shared__ __align__(16) __bf16 S[2 * 32768];   // 128KB
    const int tid  = threadIdx.x;
    const int lane = tid & 63;
    const int w    = tid >> 6;
    const int l15  = lane & 15, quad = lane >> 4;
    const int wm = w >> 2, wn = w & 3;
    const int m0 = blockIdx.y * 256, n0 = blockIdx.x * 256;
    const int NT = K >> 6;

    f32x4 acc[8][4] = {};
    bf16x8 af[4][2], bfr[2][2];

    auto stageA = [&](int T1, int h) {
        int d = T1 & 1;
        #pragma unroll
        for (int i = 0; i < 2; i++) {
            int c = i * 512 + tid;
            int lr = c >> 3, seg = c & 7;
            int g = ((lr >> 6) << 7) + h * 64 + (lr & 63);
            GLOAD_LDS16(A + (size_t)(m0 + g) * lda + T1 * 64 + ((seg ^ (lr & 7)) << 3),
                        S + d * 32768 + h * 8192 + c * 8);
        }
    };
    auto stageB = [&](int T1, int h) {
        int d = T1 & 1;
        #pragma unroll
        for (int i = 0; i < 2; i++) {
            int c = i * 512 + tid;
            int lr = c >> 3, seg = c & 7;
            int g = n0 + ((lr >> 5) << 6) + h * 32 + (lr & 31);
            if (g >= N) g = N - 1;
            GLOAD_LDS16(B + (size_t)g * K + T1 * 64 + ((seg ^ (lr & 7)) << 3),
                        S + d * 32768 + 16384 + h * 8192 + c * 8);
        }
    };

#define LOADA(d, mh) do {                                                      \
    const __bf16* Ah_ = S + (d) * 32768 + (mh) * 8192;                         \
    _Pragma("unroll")                                                          \
    for (int mi = 0; mi < 4; mi++) {                                           \
        int lr = wm * 64 + mi * 16 + l15;                                      \
        _Pragma("unroll")                                                      \
        for (int kk = 0; kk < 2; kk++)                                         \
            af[mi][kk] = *reinterpret_cast<const bf16x8*>(                     \
                Ah_ + lr * 64 + (((kk * 4 + quad) ^ (lr & 7)) << 3));          \
    }                                                                          \
} while (0)

#define LOADB(d, nh) do {                                                      \
    const __bf16* Bh_ = S + (d) * 32768 + 16384 + (nh) * 8192;                 \
    _Pragma("unroll")                                                          \
    for (int ni = 0; ni < 2; ni++) {                                           \
        int lr = wn * 32 + ni * 16 + l15;                                      \
        _Pragma("unroll")                                                      \
        for (int kk = 0; kk < 2; kk++)                                         \
            bfr[ni][kk] = *reinterpret_cast<const bf16x8*>(                    \
                Bh_ + lr * 64 + (((kk * 4 + quad) ^ (lr & 7)) << 3));          \
    }                                                                          \
} while (0)

#define SEAL() do {                                                            \
    __builtin_amdgcn_s_barrier();                                              \
    asm volatile("s_waitcnt lgkmcnt(0)" ::: "memory");                         \
    __builtin_amdgcn_sched_barrier(0);                                         \
} while (0)

#define MMA(mh, nh) do {                                                       \
    __builtin_amdgcn_s_setprio(1);                                             \
    _Pragma("unroll")                                                          \
    for (int mi = 0; mi < 4; mi++)                                             \
        _Pragma("unroll")                                                      \
        for (int ni = 0; ni < 2; ni++)                                         \
            _Pragma("unroll")                                                  \
            for (int kk = 0; kk < 2; kk++)                                     \
                acc[(mh) * 4 + mi][(nh) * 2 + ni] =                            \
                    __builtin_amdgcn_mfma_f32_16x16x32_bf16(                   \
                        af[mi][kk], bfr[ni][kk],                               \
                        acc[(mh) * 4 + mi][(nh) * 2 + ni], 0, 0, 0);           \
    __builtin_amdgcn_s_setprio(0);                                             \
} while (0)

    stageA(0, 0); stageB(0, 0); stageB(0, 1); stageA(0, 1);
    VMCNT(4);
    __builtin_amdgcn_s_barrier();

    for (int T = 0; T < NT - 1; T++) {
        const int d = T & 1;
        LOADA(d, 0); LOADB(d, 0); stageA(T + 1, 0); VMCNT(4); SEAL(); MMA(0, 0);
        LOADB(d, 1);              stageB(T + 1, 0); VMCNT(4); SEAL(); MMA(0, 1);
        LOADA(d, 1);              stageB(T + 1, 1);           SEAL(); MMA(1, 1);
        LOADB(d, 0);              stageA(T + 1, 1); VMCNT(4); SEAL(); MMA(1, 0);
    }
    {
        const int d = (NT - 1) & 1;
        LOADA(d, 0); LOADB(d, 0); VMCNT(2); SEAL(); MMA(0, 0);
        LOADB(d, 1);              VMCNT(0); SEAL(); MMA(0, 1);
        LOADA(d, 1);                        SEAL(); MMA(1, 1);
        LOADB(d, 0);                        SEAL(); MMA(1, 0);
    }
#undef LOADA
#undef LOADB
#undef SEAL
#undef MMA

    #pragma unroll
    for (int ai = 0; ai < 8; ai++) {
        #pragma unroll
        for (int bj = 0; bj < 4; bj++) {
            int col = n0 + wn * 64 + bj * 16 + l15;
            if (col < N) {
                #pragma unroll
                for (int r = 0; r < 4; r++) {
                    size_t row = m0 + wm * 128 + ai * 16 + quad * 4 + r;
                    C[row * (size_t)N + col] = (OutT)acc[ai][bj][r];
                }
            }
        }
    }
}

// ---------------- 8-phase counted-vmcnt GEMM, BM=128 (kept for out GEMM) ----
template <typename OutT>
__global__ __launch_bounds__(512) void gemm_bt_8ph(const __bf16* __restrict__ A,
                                                   int lda,
                                                   const __bf16* __restrict__ B,
                                                   OutT* __restrict__ C,
                                                   int M, int N, int K)
{
    __shared__ __align__(16) __bf16 S[2 * 24576];   // 96KB
    const int tid  = threadIdx.x;
    const int lane = tid & 63;
    const int w    = tid >> 6;
    const int l15  = lane & 15, quad = lane >> 4;
    const int wm = w >> 2, wn = w & 3;
    const int m0 = blockIdx.y * 128, n0 = blockIdx.x * 256;
    const int NT = K >> 6;

    f32x4 acc[4][4] = {};

    const int lrA = tid >> 3, segA = tid & 7;

    auto stageA = [&](int T1, int h) {
        int d = T1 & 1;
        int g = ((lrA >> 5) << 6) + h * 32 + (lrA & 31);
        GLOAD_LDS16(A + (size_t)(m0 + g) * lda + T1 * 64 + ((segA ^ (lrA & 7)) << 3),
                    S + d * 24576 + h * 4096 + tid * 8);
    };
    auto stageB = [&](int T1, int h) {
        int d = T1 & 1;
        #pragma unroll
        for (int i = 0; i < 2; i++) {
            int c = i * 512 + tid;
            int lr = c >> 3, seg = c & 7;
            int g = n0 + ((lr >> 5) << 6) + h * 32 + (lr & 31);
            if (g >= N) g = N - 1;
            GLOAD_LDS16(B + (size_t)g * K + T1 * 64 + ((seg ^ (lr & 7)) << 3),
                        S + d * 24576 + 8192 + h * 8192 + c * 8);
        }
    };

#define PHASE(d, mh, nh, STAGE, WAIT) do {                                     \
    const __bf16* Ah_ = S + (d) * 24576 + (mh) * 4096;                         \
    const __bf16* Bh_ = S + (d) * 24576 + 8192 + (nh) * 8192;                  \
    bf16x8 af[2][2], bfr[2][2];                                                \
    _Pragma("unroll")                                                          \
    for (int mr = 0; mr < 2; mr++) {                                           \
        int ar = wm * 32 + mr * 16 + l15;                                      \
        _Pragma("unroll")                                                      \
        for (int kk = 0; kk < 2; kk++)                                         \
            af[mr][kk] = *reinterpret_cast<const bf16x8*>(                     \
                Ah_ + ar * 64 + (((kk * 4 + quad) ^ (ar & 7)) << 3));          \
    }                                                                          \
    _Pragma("unroll")                                                          \
    for (int nr = 0; nr < 2; nr++) {                                           \
        int br = wn * 32 + nr * 16 + l15;                                      \
        _Pragma("unroll")                                                      \
        for (int kk = 0; kk < 2; kk++)                                         \
            bfr[nr][kk] = *reinterpret_cast<const bf16x8*>(                    \
                Bh_ + br * 64 + (((kk * 4 + quad) ^ (br & 7)) << 3));          \
    }                                                                          \
    STAGE;                                                                     \
    WAIT;                                                                      \
    __builtin_amdgcn_s_barrier();                                              \
    asm volatile("s_waitcnt lgkmcnt(0)" ::: "memory");                         \
    __builtin_amdgcn_sched_barrier(0);                                         \
    __builtin_amdgcn_s_setprio(1);                                             \
    _Pragma("unroll")                                                          \
    for (int mr = 0; mr < 2; mr++)                                             \
        _Pragma("unroll")                                                      \
        for (int nr = 0; nr < 2; nr++)                                         \
            _Pragma("unroll")                                                  \
            for (int kk = 0; kk < 2; kk++)                                     \
                acc[(mh) * 2 + mr][(nh) * 2 + nr] =                            \
                    __builtin_amdgcn_mfma_f32_16x16x32_bf16(                   \
                        af[mr][kk], bfr[nr][kk],                               \
                        acc[(mh) * 2 + mr][(nh) * 2 + nr], 0, 0, 0);           \
    __builtin_amdgcn_s_setprio(0);                                             \
} while (0)

    stageA(0, 0);
    stageB(0, 0);
    stageB(0, 1);
    stageA(0, 1);
    VMCNT(3);
    __builtin_amdgcn_s_barrier();

    for (int T = 0; T < NT - 1; T++) {
        const int d = T & 1;
        PHASE(d, 0, 0, stageA(T + 1, 0), VMCNT(2));
        PHASE(d, 0, 1, stageB(T + 1, 0), VMCNT(3));
        PHASE(d, 1, 0, stageB(T + 1, 1), (void)0);
        PHASE(d, 1, 1, stageA(T + 1, 1), VMCNT(3));
    }
    {
        const int d = (NT - 1) & 1;
        PHASE(d, 0, 0, (void)0, VMCNT(1));
        PHASE(d, 0, 1, (void)0, VMCNT(0));
        PHASE(d, 1, 0, (void)0, (void)0);
        PHASE(d, 1, 1, (void)0, (void)0);
    }
#undef PHASE

    #pragma unroll
    for (int ai = 0; ai < 4; ai++) {
        #pragma unroll
        for (int bj = 0; bj < 4; bj++) {
            int col = n0 + wn * 64 + bj * 16 + l15;
            if (col < N) {
                #pragma unroll
                for (int r = 0; r < 4; r++) {
                    size_t row = m0 + wm * 64 + ai * 16 + quad * 4 + r;
                    C[row * (size_t)N + col] = (OutT)acc[ai][bj][r];
                }
            }
        }
    }
}

// ---------------- MFMA flash attention v2.1: swapped 32x32, in-reg softmax --
// v2 structure (R5, 95us verified) + two VALU cuts:
//  (1) exp2 folding: SC2 = SCALE*log2e folded into the scale pass; every exp
//      is a bare v_exp_f32 (saves the v_mul inside __expf).
//  (2) defer-max (T13, THR=8 in log2 domain): skip the 64-mul O-rescale and
//      m-update when rmax <= m_i+8 (wave-uniform via __any). P bounded by
//      2^8=256 — safe in bf16-P / fp32-accum; exact after final 1/l.
__global__ __launch_bounds__(256, 2) void flash_mfma(
    const __bf16* __restrict__ qcat, const __bf16* __restrict__ ukv,
    const __bf16* __restrict__ vtt, __bf16* __restrict__ obuf)
{
    __shared__ __align__(16) __bf16 LDS[40960];  // KsN 2x8192 | KsR 2x4096 | Vt 2x8192

    const int tid  = threadIdx.x;
    const int w    = tid >> 6;
    const int lane = tid & 63;
    const int l31  = lane & 31;
    const int lh   = lane >> 5;
    const int l15  = lane & 15;
    const int quad = lane >> 4;
    const int gx = blockIdx.x, gy = blockIdx.y;
    int bh, qi;
    if (gy < 16) { bh = gy * 2;            qi = gx; }
    else         { bh = (gy - 16) * 2 + 1; qi = 15 - gx; }
    const int b = bh >> 4, h = bh & 15;
    const int q0 = qi * 128;
    const float SC2 = 0.10411754900f;   // (1/sqrt(192)) * log2(e)
    const size_t urow = (size_t)b * T_SEQ;

    const int q = q0 + 32 * w + l31;
    bf16x8 qf[12];
    {
        const __bf16* qrow = qcat + (urow + q) * QSTR + h * 128;
        #pragma unroll
        for (int dk = 0; dk < 8; dk++)
            qf[dk] = *reinterpret_cast<const bf16x8*>(qrow + 16 * dk + 8 * lh);
        const __bf16* qrr = qcat + (urow + q) * QSTR + 2048 + h * 64;
        #pragma unroll
        for (int dk = 0; dk < 4; dk++)
            qf[8 + dk] = *reinterpret_cast<const bf16x8*>(qrr + 16 * dk + 8 * lh);
    }

    f32x16 o[4] = {};
    float m_i = -INFINITY, l_i = 0.f;

    const int nunits = 2 * qi + 2;

    auto stage = [&](int x) {           // 10 global_load_lds per thread
        const int d1 = x & 1;
        const size_t roff = urow + (size_t)64 * x;
        #pragma unroll
        for (int p = 0; p < 4; p++) {
            int c = tid + 256 * p;
            int row = c >> 4, seg = c & 15;
            GLOAD_LDS16(ukv + (roff + row) * 4096 + h * 256 + ((seg ^ (row & 7)) << 3),
                        LDS + d1 * 8192 + c * 8);
        }
        #pragma unroll
        for (int p = 0; p < 2; p++) {
            int c = tid + 256 * p;
            int row = c >> 3, seg = c & 7;
            GLOAD_LDS16(qcat + (roff + row) * QSTR + 3072 + ((seg ^ (row & 7)) << 3),
                        LDS + 16384 + d1 * 4096 + c * 8);
        }
        const __bf16* vsrc = vtt + ((size_t)bh * 32 + x) * 8192;
        #pragma unroll
        for (int p = 0; p < 4; p++) {
            int c = tid + 256 * p;
            GLOAD_LDS16(vsrc + c * 8, LDS + 24576 + d1 * 8192 + c * 8);
        }
    };

    stage(0);
    VMCNT(0);
    __builtin_amdgcn_s_barrier();

    for (int u = 0; u < nunits; u++) {
        if (u + 1 < nunits) { stage(u + 1); VMCNT(10); }
        else                { VMCNT(0); }
        __builtin_amdgcn_s_barrier();
        __builtin_amdgcn_sched_barrier(0);

        const int d1 = u & 1;
        const __bf16* KN = LDS + d1 * 8192;
        const __bf16* KR = LDS + 16384 + d1 * 4096;
        const __bf16* VT = LDS + 24576 + d1 * 8192;
        const int key = l31 & 7;

        f32x16 s2[2] = {};
        __builtin_amdgcn_s_setprio(1);
        #pragma unroll
        for (int t = 0; t < 2; t++) {
            const __bf16* kn = KN + (32 * t + l31) * 128;
            const __bf16* kr = KR + (32 * t + l31) * 64;
            #pragma unroll
            for (int dk = 0; dk < 8; dk++) {
                bf16x8 kf = *reinterpret_cast<const bf16x8*>(kn + (((2 * dk + lh) ^ key) << 3));
                s2[t] = __builtin_amdgcn_mfma_f32_32x32x16_bf16(kf, qf[dk], s2[t], 0, 0, 0);
            }
            #pragma unroll
            for (int dk = 0; dk < 4; dk++) {
                bf16x8 kf = *reinterpret_cast<const bf16x8*>(kr + (((2 * dk + lh) ^ key) << 3));
                s2[t] = __builtin_amdgcn_mfma_f32_32x32x16_bf16(kf, qf[8 + dk], s2[t], 0, 0, 0);
            }
        }
        __builtin_amdgcn_s_setprio(0);

        const int k0 = 64 * u;
        const bool domask = (u + 2 >= nunits);
        float rmax = -INFINITY;
        #pragma unroll
        for (int t = 0; t < 2; t++)
            #pragma unroll
            for (int g = 0; g < 16; g++) {
                float v = s2[t][g] * SC2;        // log2-domain scores
                if (domask) {
                    int kg = k0 + 32 * t + (g & 3) + 8 * (g >> 2) + 4 * lh;
                    if (kg > q) v = -INFINITY;
                }
                s2[t][g] = v;
                rmax = fmaxf(rmax, v);
            }
        rmax = fmaxf(rmax, __shfl_xor(rmax, 32, 64));
        // defer-max: only rescale when the running max grew by > 8 (log2)
        if (__any(rmax > m_i + 8.0f)) {
            const float mnew  = fmaxf(m_i, rmax);
            const float alpha = fexp2(m_i - mnew);
            m_i = mnew;
            l_i *= alpha;
            #pragma unroll
            for (int dt = 0; dt < 4; dt++) o[dt] *= alpha;
        }
        float part = 0.f;
        #pragma unroll
        for (int t = 0; t < 2; t++)
            #pragma unroll
            for (int g = 0; g < 16; g++) {
                float pv = fexp2(s2[t][g] - m_i);   // bounded by 2^8
                s2[t][g] = pv;
                part += pv;
            }
        l_i += part;

        __builtin_amdgcn_s_setprio(1);
        #pragma unroll
        for (int t = 0; t < 2; t++) {
            unsigned Ap[4], Bp[4];
            #pragma unroll
            for (int g = 0; g < 4; g++) {
                Ap[g] = cvtpk_bf16(s2[t][4 * g],     s2[t][4 * g + 1]);
                Bp[g] = cvtpk_bf16(s2[t][4 * g + 2], s2[t][4 * g + 3]);
            }
            #pragma unroll
            for (int sub = 0; sub < 2; sub++) {
                unsigned xA = lh ? Ap[2 * sub] : Ap[2 * sub + 1];
                unsigned xB = lh ? Bp[2 * sub] : Bp[2 * sub + 1];
                unsigned rA = __shfl_xor(xA, 32, 64);
                unsigned rB = __shfl_xor(xB, 32, 64);
                u32x4 uv;
                uv[0] = lh ? rA : Ap[2 * sub];
                uv[1] = lh ? rB : Bp[2 * sub];
                uv[2] = lh ? Ap[2 * sub + 1] : rA;
                uv[3] = lh ? Bp[2 * sub + 1] : rB;
                bf16x8 pf = __builtin_bit_cast(bf16x8, uv);
                const int s = 2 * t + sub;
                #pragma unroll
                for (int dt = 0; dt < 4; dt++) {
                    bf16x8 vf = *reinterpret_cast<const bf16x8*>(
                        VT + (32 * dt + l31) * 64 + (((2 * s + lh) ^ key) << 3));
                    o[dt] = __builtin_amdgcn_mfma_f32_32x32x16_bf16(vf, pf, o[dt], 0, 0, 0);
                }
            }
        }
        __builtin_amdgcn_s_setprio(0);

        __builtin_amdgcn_sched_barrier(0);
        __builtin_amdgcn_s_barrier();
    }

    const float linv = 1.0f / (l_i + __shfl_xor(l_i, 32, 64));
    float* Os = reinterpret_cast<float*>(LDS);     // [128 q][132 d]
    #pragma unroll
    for (int dt = 0; dt < 4; dt++)
        #pragma unroll
        for (int g = 0; g < 16; g++) {
            int d = 32 * dt + (g & 3) + 8 * (g >> 2) + 4 * lh;
            Os[(32 * w + l31) * 132 + d] = o[dt][g] * linv;
        }
    asm volatile("s_waitcnt lgkmcnt(0)" ::: "memory");
    __builtin_amdgcn_sched_barrier(0);
    #pragma unroll
    for (int p = 0; p < 8; p++) {
        int row = 32 * w + 4 * p + quad;
        float4 a4 = *reinterpret_cast<const float4*>(Os + row * 132 + 8 * l15);
        float4 c2 = *reinterpret_cast<const float4*>(Os + row * 132 + 8 * l15 + 4);
        bf16x8 f;
        f[0] = (__bf16)a4.x; f[1] = (__bf16)a4.y; f[2] = (__bf16)a4.z; f[3] = (__bf16)a4.w;
        f[4] = (__bf16)c2.x; f[5] = (__bf16)c2.y; f[6] = (__bf16)c2.z; f[7] = (__bf16)c2.w;
        *reinterpret_cast<bf16x8*>(obuf + (urow + q0 + row) * 2048 + h * 128 + 8 * l15) = f;
    }
}

extern "C" void kernel_launch(void* const* d_in, const int* in_sizes, int n_in,
                              void* d_out, int out_size, void* d_ws, size_t ws_size,
                              hipStream_t stream)
{
    const float* x      = (const float*)d_in[0];
    const float* w_q    = (const float*)d_in[1];
    const float* w_dkv  = (const float*)d_in[2];
    const float* w_ukv  = (const float*)d_in[3];
    const float* w_o    = (const float*)d_in[4];
    const float* w_qrot = (const float*)d_in[5];
    const float* w_krot = (const float*)d_in[6];
    float* out = (float*)d_out;

    const size_t M = 4096;
    __bf16* ws   = (__bf16*)d_ws;
    __bf16* xb   = ws;                        // 4096x2048
    __bf16* wcat = xb + M * 2048;             // 3648x2048 = [w_q|w_qrot|w_krot|w_dkv]
    __bf16* wqb  = wcat;
    __bf16* wqrb = wcat + (size_t)2048 * 2048;
    __bf16* wkrb = wqrb + (size_t)1024 * 2048;
    __bf16* wdkb = wkrb + (size_t)64 * 2048;
    __bf16* wukb = wcat + (size_t)QSTR * 2048; // 4096x512
    __bf16* wob  = wukb + (size_t)4096 * 512;  // 2048x2048
    __bf16* qcat = wob  + (size_t)2048 * 2048; // 4096x3648 (q|qrot|krot|dkv)
    __bf16* ukv  = qcat + M * QSTR;            // 4096x4096
    __bf16* ao   = ukv  + M * 4096;            // 4096x2048
    __bf16* vtt  = ao   + M * 2048;            // 1024 tiles x 128x64 (~16.8MB)

    dim3 blk(256);

    CastArgs ca;
    ca.s[0] = x;      ca.d[0] = xb;
    ca.s[1] = w_q;    ca.d[1] = wqb;
    ca.s[2] = w_qrot; ca.d[2] = wqrb;
    ca.s[3] = w_krot; ca.d[3] = wkrb;
    ca.s[4] = w_dkv;  ca.d[4] = wdkb;
    ca.s[5] = w_ukv;  ca.d[5] = wukb;
    ca.s[6] = w_o;    ca.d[6] = wob;
    ca.cum[0] = 0;
    ca.cum[1] = ca.cum[0] + 4096;
    ca.cum[2] = ca.cum[1] + 2048;
    ca.cum[3] = ca.cum[2] + 1024;
    ca.cum[4] = ca.cum[3] + 64;
    ca.cum[5] = ca.cum[4] + 512;
    ca.cum[6] = ca.cum[5] + 1024;
    ca.cum[7] = ca.cum[6] + 2048;
    cast_all<<<ca.cum[7], blk, 0, stream>>>(ca);

    gemm_bt_256<__bf16><<<dim3(15, 16), dim3(512), 0, stream>>>(
        xb, 2048, wcat, qcat, 4096, QSTR, 2048);
    gemm_bt_256<__bf16><<<dim3(16, 16), dim3(512), 0, stream>>>(
        qcat + 3136, QSTR, wukb, ukv, 4096, 4096, 512);

    rope_ip<<<8192, blk, 0, stream>>>(qcat + 2048, 9, QSTR, 4096 * 512);
    rope_ip<<<512,  blk, 0, stream>>>(qcat + 3072, 5, QSTR, 4096 * 32);
    prep_v<<<dim3(32, 32), blk, 0, stream>>>(ukv, vtt);

    flash_mfma<<<dim3(16, 32), dim3(256), 0, stream>>>(qcat, ukv, vtt, ao);

    gemm_bt_8ph<float><<<dim3(8, 32), dim3(512), 0, stream>>>(
        ao, 2048, wob, out, 4096, 2048, 2048);
}

// Round 10
// 354.898 us; speedup vs baseline: 1.0830x; 1.0272x over previous
//
#include <hip/hip_runtime.h>
#include <hip/hip_bf16.h>
#include <math.h>

#define T_SEQ 2048
#define QSTR  3648   // combined q|qrot|krot|dkv row stride

typedef __bf16 bf16x8 __attribute__((ext_vector_type(8)));
typedef float  f32x4  __attribute__((ext_vector_type(4)));
typedef float  f32x16 __attribute__((ext_vector_type(16)));
typedef unsigned int u32x4 __attribute__((ext_vector_type(4)));

#define GLOAD_LDS16(g, l) __builtin_amdgcn_global_load_lds( \
    (const __attribute__((address_space(1))) void*)(g),      \
    (__attribute__((address_space(3))) void*)(l), 16, 0, 0)

#define VMCNT(n) asm volatile("s_waitcnt vmcnt(" #n ")" ::: "memory")

static __device__ __forceinline__ unsigned cvtpk_bf16(float a, float b)
{
    unsigned r;
    asm("v_cvt_pk_bf16_f32 %0, %1, %2" : "=v"(r) : "v"(a), "v"(b));
    return r;
}

static __device__ __forceinline__ float fexp2(float x)
{
    float r;
    asm("v_exp_f32 %0, %1" : "=v"(r) : "v"(x));
    return r;
}

// ---------------- fused fp32 -> bf16 cast for all 7 buffers ----------------
struct CastArgs {
    const float* s[7];
    __bf16*      d[7];
    unsigned     cum[8];    // cumulative block counts (2048 elements per block)
};

__global__ __launch_bounds__(256) void cast_all(CastArgs a)
{
    const unsigned blk = blockIdx.x;
    int idx = 0;
    #pragma unroll
    for (int i = 1; i < 7; i++) if (blk >= a.cum[i]) idx = i;
    const unsigned local = blk - a.cum[idx];
    const float* src = a.s[idx];
    __bf16* dst = a.d[idx];
    const int i = (int)(local * 256 + threadIdx.x) * 8;
    float4 va = *reinterpret_cast<const float4*>(src + i);
    float4 vb = *reinterpret_cast<const float4*>(src + i + 4);
    bf16x8 f;
    f[0] = (__bf16)va.x; f[1] = (__bf16)va.y; f[2] = (__bf16)va.z; f[3] = (__bf16)va.w;
    f[4] = (__bf16)vb.x; f[5] = (__bf16)vb.y; f[6] = (__bf16)vb.z; f[7] = (__bf16)vb.w;
    *reinterpret_cast<bf16x8*>(dst + i) = f;
}

// ---------------- merged in-place RoPE (qrot + krot in one dispatch) --------
// blocks [0,8192): qrot (shift 9); blocks [8192,8704): krot (shift 5).
__global__ __launch_bounds__(256) void rope_all(__bf16* qcat)
{
    const unsigned blk = blockIdx.x;
    __bf16* buf;
    int shift, gid;
    if (blk < 8192) { buf = qcat + 2048; shift = 9; gid = blk * 256 + threadIdx.x; }
    else            { buf = qcat + 3072; shift = 5; gid = (blk - 8192) * 256 + threadIdx.x; }
    int row = gid >> shift;
    int rem = gid & ((1 << shift) - 1);
    int hb = rem >> 5, j = rem & 31;
    int t = row & (T_SEQ - 1);
    const float L2B = 0.4152410118609203f;      // log2(10000)/32
    float freq = exp2f(-L2B * (float)j);
    float sn, cs;
    __sincosf((float)t * freq, &sn, &cs);
    size_t base = (size_t)row * QSTR + hb * 64 + j;
    float v1 = (float)buf[base], v2 = (float)buf[base + 32];
    buf[base]      = (__bf16)(v1 * cs - v2 * sn);
    buf[base + 32] = (__bf16)(v2 * cs + v1 * sn);
}

// ---------------- V pre-transpose: vtt[bh][u][dv(128)][k(64)] XOR-swizzled ---
__global__ __launch_bounds__(256) void prep_v(const __bf16* __restrict__ ukv,
                                              __bf16* __restrict__ vtt)
{
    __shared__ __align__(16) __bf16 Ls[64 * 136];
    const int tid = threadIdx.x;
    const int u = blockIdx.x, bh = blockIdx.y;
    const int b = bh >> 4, h = bh & 15;
    const size_t base = (size_t)b * T_SEQ + u * 64;
    #pragma unroll
    for (int p = 0; p < 4; p++) {
        int c = tid + 256 * p;
        int k = c >> 4, dv8 = (c & 15) * 8;
        *reinterpret_cast<bf16x8*>(Ls + k * 136 + dv8) =
            *reinterpret_cast<const bf16x8*>(ukv + (base + k) * 4096 + h * 256 + 128 + dv8);
    }
    __syncthreads();
    #pragma unroll
    for (int p = 0; p < 4; p++) {
        int c = tid + 256 * p;
        int dv = c >> 3, kb = c & 7;
        bf16x8 f;
        #pragma unroll
        for (int i = 0; i < 8; i++) f[i] = Ls[(kb * 8 + i) * 136 + dv];
        *reinterpret_cast<bf16x8*>(vtt + (((size_t)bh * 32 + u) * 128 + dv) * 64
                                   + ((kb ^ (dv & 7)) << 3)) = f;
    }
}

// ---------------- 256x256 snake-phase counted-vmcnt GEMM (+XCD swizzle) -----
template <typename OutT>
__global__ __launch_bounds__(512, 2) void gemm_bt_256(const __bf16* __restrict__ A,
                                                      int lda,
                                                      const __bf16* __restrict__ B,
                                                      OutT* __restrict__ C,
                                                      int M, int N, int K)
{
    __shared__ __align__(16) __bf16 S[2 * 32768];   // 128KB
    const int tid  = threadIdx.x;
    const int lane = tid & 63;
    const int w    = tid >> 6;
    const int l15  = lane & 15, quad = lane >> 4;
    const int wm = w >> 2, wn = w & 3;
    // bijective XCD swizzle (requires nwg % 8 == 0): XCD x gets a contiguous
    // chunk of tiles -> A/B panel reuse within that XCD's L2.
    const unsigned nwg = gridDim.x * gridDim.y;
    const unsigned fid = blockIdx.y * gridDim.x + blockIdx.x;
    const unsigned swz = (fid & 7) * (nwg >> 3) + (fid >> 3);
    const int m0 = (int)(swz / gridDim.x) * 256, n0 = (int)(swz % gridDim.x) * 256;
    const int NT = K >> 6;

    f32x4 acc[8][4] = {};
    bf16x8 af[4][2], bfr[2][2];

    auto stageA = [&](int T1, int h) {
        int d = T1 & 1;
        #pragma unroll
        for (int i = 0; i < 2; i++) {
            int c = i * 512 + tid;
            int lr = c >> 3, seg = c & 7;
            int g = ((lr >> 6) << 7) + h * 64 + (lr & 63);
            GLOAD_LDS16(A + (size_t)(m0 + g) * lda + T1 * 64 + ((seg ^ (lr & 7)) << 3),
                        S + d * 32768 + h * 8192 + c * 8);
        }
    };
    auto stageB = [&](int T1, int h) {
        int d = T1 & 1;
        #pragma unroll
        for (int i = 0; i < 2; i++) {
            int c = i * 512 + tid;
            int lr = c >> 3, seg = c & 7;
            int g = n0 + ((lr >> 5) << 6) + h * 32 + (lr & 31);
            if (g >= N) g = N - 1;
            GLOAD_LDS16(B + (size_t)g * K + T1 * 64 + ((seg ^ (lr & 7)) << 3),
                        S + d * 32768 + 16384 + h * 8192 + c * 8);
        }
    };

#define LOADA(d, mh) do {                                                      \
    const __bf16* Ah_ = S + (d) * 32768 + (mh) * 8192;                         \
    _Pragma("unroll")                                                          \
    for (int mi = 0; mi < 4; mi++) {                                           \
        int lr = wm * 64 + mi * 16 + l15;                                      \
        _Pragma("unroll")                                                      \
        for (int kk = 0; kk < 2; kk++)                                         \
            af[mi][kk] = *reinterpret_cast<const bf16x8*>(                     \
                Ah_ + lr * 64 + (((kk * 4 + quad) ^ (lr & 7)) << 3));          \
    }                                                                          \
} while (0)

#define LOADB(d, nh) do {                                                      \
    const __bf16* Bh_ = S + (d) * 32768 + 16384 + (nh) * 8192;                 \
    _Pragma("unroll")                                                          \
    for (int ni = 0; ni < 2; ni++) {                                           \
        int lr = wn * 32 + ni * 16 + l15;                                      \
        _Pragma("unroll")                                                      \
        for (int kk = 0; kk < 2; kk++)                                         \
            bfr[ni][kk] = *reinterpret_cast<const bf16x8*>(                    \
                Bh_ + lr * 64 + (((kk * 4 + quad) ^ (lr & 7)) << 3));          \
    }                                                                          \
} while (0)

#define SEAL() do {                                                            \
    __builtin_amdgcn_s_barrier();                                              \
    asm volatile("s_waitcnt lgkmcnt(0)" ::: "memory");                         \
    __builtin_amdgcn_sched_barrier(0);                                         \
} while (0)

#define MMA(mh, nh) do {                                                       \
    __builtin_amdgcn_s_setprio(1);                                             \
    _Pragma("unroll")                                                          \
    for (int mi = 0; mi < 4; mi++)                                             \
        _Pragma("unroll")                                                      \
        for (int ni = 0; ni < 2; ni++)                                         \
            _Pragma("unroll")                                                  \
            for (int kk = 0; kk < 2; kk++)                                     \
                acc[(mh) * 4 + mi][(nh) * 2 + ni] =                            \
                    __builtin_amdgcn_mfma_f32_16x16x32_bf16(                   \
                        af[mi][kk], bfr[ni][kk],                               \
                        acc[(mh) * 4 + mi][(nh) * 2 + ni], 0, 0, 0);           \
    __builtin_amdgcn_s_setprio(0);                                             \
} while (0)

    stageA(0, 0); stageB(0, 0); stageB(0, 1); stageA(0, 1);
    VMCNT(4);
    __builtin_amdgcn_s_barrier();

    for (int T = 0; T < NT - 1; T++) {
        const int d = T & 1;
        LOADA(d, 0); LOADB(d, 0); stageA(T + 1, 0); VMCNT(4); SEAL(); MMA(0, 0);
        LOADB(d, 1);              stageB(T + 1, 0); VMCNT(4); SEAL(); MMA(0, 1);
        LOADA(d, 1);              stageB(T + 1, 1);           SEAL(); MMA(1, 1);
        LOADB(d, 0);              stageA(T + 1, 1); VMCNT(4); SEAL(); MMA(1, 0);
    }
    {
        const int d = (NT - 1) & 1;
        LOADA(d, 0); LOADB(d, 0); VMCNT(2); SEAL(); MMA(0, 0);
        LOADB(d, 1);              VMCNT(0); SEAL(); MMA(0, 1);
        LOADA(d, 1);                        SEAL(); MMA(1, 1);
        LOADB(d, 0);                        SEAL(); MMA(1, 0);
    }
#undef LOADA
#undef LOADB
#undef SEAL
#undef MMA

    #pragma unroll
    for (int ai = 0; ai < 8; ai++) {
        #pragma unroll
        for (int bj = 0; bj < 4; bj++) {
            int col = n0 + wn * 64 + bj * 16 + l15;
            if (col < N) {
                #pragma unroll
                for (int r = 0; r < 4; r++) {
                    size_t row = m0 + wm * 128 + ai * 16 + quad * 4 + r;
                    C[row * (size_t)N + col] = (OutT)acc[ai][bj][r];
                }
            }
        }
    }
}

// ---------------- 8-phase counted-vmcnt GEMM, BM=128 (+XCD swizzle) ---------
template <typename OutT>
__global__ __launch_bounds__(512) void gemm_bt_8ph(const __bf16* __restrict__ A,
                                                   int lda,
                                                   const __bf16* __restrict__ B,
                                                   OutT* __restrict__ C,
                                                   int M, int N, int K)
{
    __shared__ __align__(16) __bf16 S[2 * 24576];   // 96KB
    const int tid  = threadIdx.x;
    const int lane = tid & 63;
    const int w    = tid >> 6;
    const int l15  = lane & 15, quad = lane >> 4;
    const int wm = w >> 2, wn = w & 3;
    const unsigned nwg = gridDim.x * gridDim.y;
    const unsigned fid = blockIdx.y * gridDim.x + blockIdx.x;
    const unsigned swz = (fid & 7) * (nwg >> 3) + (fid >> 3);
    const int m0 = (int)(swz / gridDim.x) * 128, n0 = (int)(swz % gridDim.x) * 256;
    const int NT = K >> 6;

    f32x4 acc[4][4] = {};

    const int lrA = tid >> 3, segA = tid & 7;

    auto stageA = [&](int T1, int h) {
        int d = T1 & 1;
        int g = ((lrA >> 5) << 6) + h * 32 + (lrA & 31);
        GLOAD_LDS16(A + (size_t)(m0 + g) * lda + T1 * 64 + ((segA ^ (lrA & 7)) << 3),
                    S + d * 24576 + h * 4096 + tid * 8);
    };
    auto stageB = [&](int T1, int h) {
        int d = T1 & 1;
        #pragma unroll
        for (int i = 0; i < 2; i++) {
            int c = i * 512 + tid;
            int lr = c >> 3, seg = c & 7;
            int g = n0 + ((lr >> 5) << 6) + h * 32 + (lr & 31);
            if (g >= N) g = N - 1;
            GLOAD_LDS16(B + (size_t)g * K + T1 * 64 + ((seg ^ (lr & 7)) << 3),
                        S + d * 24576 + 8192 + h * 8192 + c * 8);
        }
    };

#define PHASE(d, mh, nh, STAGE, WAIT) do {                                     \
    const __bf16* Ah_ = S + (d) * 24576 + (mh) * 4096;                         \
    const __bf16* Bh_ = S + (d) * 24576 + 8192 + (nh) * 8192;                  \
    bf16x8 af[2][2], bfr[2][2];                                                \
    _Pragma("unroll")                                                          \
    for (int mr = 0; mr < 2; mr++) {                                           \
        int ar = wm * 32 + mr * 16 + l15;                                      \
        _Pragma("unroll")                                                      \
        for (int kk = 0; kk < 2; kk++)                                         \
            af[mr][kk] = *reinterpret_cast<const bf16x8*>(                     \
                Ah_ + ar * 64 + (((kk * 4 + quad) ^ (ar & 7)) << 3));          \
    }                                                                          \
    _Pragma("unroll")                                                          \
    for (int nr = 0; nr < 2; nr++) {                                           \
        int br = wn * 32 + nr * 16 + l15;                                      \
        _Pragma("unroll")                                                      \
        for (int kk = 0; kk < 2; kk++)                                         \
            bfr[nr][kk] = *reinterpret_cast<const bf16x8*>(                    \
                Bh_ + br * 64 + (((kk * 4 + quad) ^ (br & 7)) << 3));          \
    }                                                                          \
    STAGE;                                                                     \
    WAIT;                                                                      \
    __builtin_amdgcn_s_barrier();                                              \
    asm volatile("s_waitcnt lgkmcnt(0)" ::: "memory");                         \
    __builtin_amdgcn_sched_barrier(0);                                         \
    __builtin_amdgcn_s_setprio(1);                                             \
    _Pragma("unroll")                                                          \
    for (int mr = 0; mr < 2; mr++)                                             \
        _Pragma("unroll")                                                      \
        for (int nr = 0; nr < 2; nr++)                                         \
            _Pragma("unroll")                                                  \
            for (int kk = 0; kk < 2; kk++)                                     \
                acc[(mh) * 2 + mr][(nh) * 2 + nr] =                            \
                    __builtin_amdgcn_mfma_f32_16x16x32_bf16(                   \
                        af[mr][kk], bfr[nr][kk],                               \
                        acc[(mh) * 2 + mr][(nh) * 2 + nr], 0, 0, 0);           \
    __builtin_amdgcn_s_setprio(0);                                             \
} while (0)

    stageA(0, 0);
    stageB(0, 0);
    stageB(0, 1);
    stageA(0, 1);
    VMCNT(3);
    __builtin_amdgcn_s_barrier();

    for (int T = 0; T < NT - 1; T++) {
        const int d = T & 1;
        PHASE(d, 0, 0, stageA(T + 1, 0), VMCNT(2));
        PHASE(d, 0, 1, stageB(T + 1, 0), VMCNT(3));
        PHASE(d, 1, 0, stageB(T + 1, 1), (void)0);
        PHASE(d, 1, 1, stageA(T + 1, 1), VMCNT(3));
    }
    {
        const int d = (NT - 1) & 1;
        PHASE(d, 0, 0, (void)0, VMCNT(1));
        PHASE(d, 0, 1, (void)0, VMCNT(0));
        PHASE(d, 1, 0, (void)0, (void)0);
        PHASE(d, 1, 1, (void)0, (void)0);
    }
#undef PHASE

    #pragma unroll
    for (int ai = 0; ai < 4; ai++) {
        #pragma unroll
        for (int bj = 0; bj < 4; bj++) {
            int col = n0 + wn * 64 + bj * 16 + l15;
            if (col < N) {
                #pragma unroll
                for (int r = 0; r < 4; r++) {
                    size_t row = m0 + wm * 64 + ai * 16 + quad * 4 + r;
                    C[row * (size_t)N + col] = (OutT)acc[ai][bj][r];
                }
            }
        }
    }
}

// ---------------- MFMA flash attention v2.2: per-t pipelined softmax --------
// v2.1 (R9, 91.7us verified) + per-t split: tile t=0 is fully processed
// (mask/exp/pack/PV) before t=1's softmax; t=1's QK MFMAs are issued first so
// softmax(t0) VALU hides under QK(t1) latency, softmax(t1) under PV(t0).
// Algebraically identical to two sequential online-softmax updates.
__global__ __launch_bounds__(256, 2) void flash_mfma(
    const __bf16* __restrict__ qcat, const __bf16* __restrict__ ukv,
    const __bf16* __restrict__ vtt, __bf16* __restrict__ obuf)
{
    __shared__ __align__(16) __bf16 LDS[40960];  // KsN 2x8192 | KsR 2x4096 | Vt 2x8192

    const int tid  = threadIdx.x;
    const int w    = tid >> 6;
    const int lane = tid & 63;
    const int l31  = lane & 31;
    const int lh   = lane >> 5;
    const int l15  = lane & 15;
    const int quad = lane >> 4;
    const int gx = blockIdx.x, gy = blockIdx.y;
    int bh, qi;
    if (gy < 16) { bh = gy * 2;            qi = gx; }
    else         { bh = (gy - 16) * 2 + 1; qi = 15 - gx; }
    const int b = bh >> 4, h = bh & 15;
    const int q0 = qi * 128;
    const float SC2 = 0.10411754900f;   // (1/sqrt(192)) * log2(e)
    const size_t urow = (size_t)b * T_SEQ;

    const int q = q0 + 32 * w + l31;
    bf16x8 qf[12];
    {
        const __bf16* qrow = qcat + (urow + q) * QSTR + h * 128;
        #pragma unroll
        for (int dk = 0; dk < 8; dk++)
            qf[dk] = *reinterpret_cast<const bf16x8*>(qrow + 16 * dk + 8 * lh);
        const __bf16* qrr = qcat + (urow + q) * QSTR + 2048 + h * 64;
        #pragma unroll
        for (int dk = 0; dk < 4; dk++)
            qf[8 + dk] = *reinterpret_cast<const bf16x8*>(qrr + 16 * dk + 8 * lh);
    }

    f32x16 o[4] = {};
    float m_i = -INFINITY, l_i = 0.f;

    const int nunits = 2 * qi + 2;

    auto stage = [&](int x) {           // 10 global_load_lds per thread
        const int d1 = x & 1;
        const size_t roff = urow + (size_t)64 * x;
        #pragma unroll
        for (int p = 0; p < 4; p++) {
            int c = tid + 256 * p;
            int row = c >> 4, seg = c & 15;
            GLOAD_LDS16(ukv + (roff + row) * 4096 + h * 256 + ((seg ^ (row & 7)) << 3),
                        LDS + d1 * 8192 + c * 8);
        }
        #pragma unroll
        for (int p = 0; p < 2; p++) {
            int c = tid + 256 * p;
            int row = c >> 3, seg = c & 7;
            GLOAD_LDS16(qcat + (roff + row) * QSTR + 3072 + ((seg ^ (row & 7)) << 3),
                        LDS + 16384 + d1 * 4096 + c * 8);
        }
        const __bf16* vsrc = vtt + ((size_t)bh * 32 + x) * 8192;
        #pragma unroll
        for (int p = 0; p < 4; p++) {
            int c = tid + 256 * p;
            GLOAD_LDS16(vsrc + c * 8, LDS + 24576 + d1 * 8192 + c * 8);
        }
    };

    stage(0);
    VMCNT(0);
    __builtin_amdgcn_s_barrier();

    for (int u = 0; u < nunits; u++) {
        if (u + 1 < nunits) { stage(u + 1); VMCNT(10); }
        else                { VMCNT(0); }
        __builtin_amdgcn_s_barrier();
        __builtin_amdgcn_sched_barrier(0);

        const int d1 = u & 1;
        const __bf16* KN = LDS + d1 * 8192;
        const __bf16* KR = LDS + 16384 + d1 * 4096;
        const __bf16* VT = LDS + 24576 + d1 * 8192;
        const int key = l31 & 7;
        const int k0 = 64 * u;
        const bool domask = (u + 2 >= nunits);

        // ---- QK for both 32x32 tiles (24 MFMA issued up front) ----
        f32x16 s2[2] = {};
        __builtin_amdgcn_s_setprio(1);
        #pragma unroll
        for (int t = 0; t < 2; t++) {
            const __bf16* kn = KN + (32 * t + l31) * 128;
            const __bf16* kr = KR + (32 * t + l31) * 64;
            #pragma unroll
            for (int dk = 0; dk < 8; dk++) {
                bf16x8 kf = *reinterpret_cast<const bf16x8*>(kn + (((2 * dk + lh) ^ key) << 3));
                s2[t] = __builtin_amdgcn_mfma_f32_32x32x16_bf16(kf, qf[dk], s2[t], 0, 0, 0);
            }
            #pragma unroll
            for (int dk = 0; dk < 4; dk++) {
                bf16x8 kf = *reinterpret_cast<const bf16x8*>(kr + (((2 * dk + lh) ^ key) << 3));
                s2[t] = __builtin_amdgcn_mfma_f32_32x32x16_bf16(kf, qf[8 + dk], s2[t], 0, 0, 0);
            }
        }
        __builtin_amdgcn_s_setprio(0);

        // ---- per-t: softmax(t) then PV(t); softmax(t0) overlaps QK(t1),
        //      softmax(t1) overlaps PV(t0) in the in-order issue stream ----
        #pragma unroll
        for (int t = 0; t < 2; t++) {
            float rmax = -INFINITY;
            #pragma unroll
            for (int g = 0; g < 16; g++) {
                float v = s2[t][g] * SC2;        // log2-domain scores
                if (domask) {
                    int kg = k0 + 32 * t + (g & 3) + 8 * (g >> 2) + 4 * lh;
                    if (kg > q) v = -INFINITY;
                }
                s2[t][g] = v;
                rmax = fmaxf(rmax, v);
            }
            rmax = fmaxf(rmax, __shfl_xor(rmax, 32, 64));
            if (__any(rmax > m_i + 8.0f)) {      // defer-max (T13)
                const float mnew  = fmaxf(m_i, rmax);
                const float alpha = fexp2(m_i - mnew);
                m_i = mnew;
                l_i *= alpha;
                #pragma unroll
                for (int dt = 0; dt < 4; dt++) o[dt] *= alpha;
            }
            float part = 0.f;
            #pragma unroll
            for (int g = 0; g < 16; g++) {
                float pv = fexp2(s2[t][g] - m_i);   // bounded by 2^8
                s2[t][g] = pv;
                part += pv;
            }
            l_i += part;

            __builtin_amdgcn_s_setprio(1);
            unsigned Ap[4], Bp[4];
            #pragma unroll
            for (int g = 0; g < 4; g++) {
                Ap[g] = cvtpk_bf16(s2[t][4 * g],     s2[t][4 * g + 1]);
                Bp[g] = cvtpk_bf16(s2[t][4 * g + 2], s2[t][4 * g + 3]);
            }
            #pragma unroll
            for (int sub = 0; sub < 2; sub++) {
                unsigned xA = lh ? Ap[2 * sub] : Ap[2 * sub + 1];
                unsigned xB = lh ? Bp[2 * sub] : Bp[2 * sub + 1];
                unsigned rA = __shfl_xor(xA, 32, 64);
                unsigned rB = __shfl_xor(xB, 32, 64);
                u32x4 uv;
                uv[0] = lh ? rA : Ap[2 * sub];
                uv[1] = lh ? rB : Bp[2 * sub];
                uv[2] = lh ? Ap[2 * sub + 1] : rA;
                uv[3] = lh ? Bp[2 * sub + 1] : rB;
                bf16x8 pf = __builtin_bit_cast(bf16x8, uv);
                const int s = 2 * t + sub;
                #pragma unroll
                for (int dt = 0; dt < 4; dt++) {
                    bf16x8 vf = *reinterpret_cast<const bf16x8*>(
                        VT + (32 * dt + l31) * 64 + (((2 * s + lh) ^ key) << 3));
                    o[dt] = __builtin_amdgcn_mfma_f32_32x32x16_bf16(vf, pf, o[dt], 0, 0, 0);
                }
            }
            __builtin_amdgcn_s_setprio(0);
        }

        __builtin_amdgcn_sched_barrier(0);
        __builtin_amdgcn_s_barrier();
    }

    const float linv = 1.0f / (l_i + __shfl_xor(l_i, 32, 64));
    float* Os = reinterpret_cast<float*>(LDS);     // [128 q][132 d]
    #pragma unroll
    for (int dt = 0; dt < 4; dt++)
        #pragma unroll
        for (int g = 0; g < 16; g++) {
            int d = 32 * dt + (g & 3) + 8 * (g >> 2) + 4 * lh;
            Os[(32 * w + l31) * 132 + d] = o[dt][g] * linv;
        }
    asm volatile("s_waitcnt lgkmcnt(0)" ::: "memory");
    __builtin_amdgcn_sched_barrier(0);
    #pragma unroll
    for (int p = 0; p < 8; p++) {
        int row = 32 * w + 4 * p + quad;
        float4 a4 = *reinterpret_cast<const float4*>(Os + row * 132 + 8 * l15);
        float4 c2 = *reinterpret_cast<const float4*>(Os + row * 132 + 8 * l15 + 4);
        bf16x8 f;
        f[0] = (__bf16)a4.x; f[1] = (__bf16)a4.y; f[2] = (__bf16)a4.z; f[3] = (__bf16)a4.w;
        f[4] = (__bf16)c2.x; f[5] = (__bf16)c2.y; f[6] = (__bf16)c2.z; f[7] = (__bf16)c2.w;
        *reinterpret_cast<bf16x8*>(obuf + (urow + q0 + row) * 2048 + h * 128 + 8 * l15) = f;
    }
}

extern "C" void kernel_launch(void* const* d_in, const int* in_sizes, int n_in,
                              void* d_out, int out_size, void* d_ws, size_t ws_size,
                              hipStream_t stream)
{
    const float* x      = (const float*)d_in[0];
    const float* w_q    = (const float*)d_in[1];
    const float* w_dkv  = (const float*)d_in[2];
    const float* w_ukv  = (const float*)d_in[3];
    const float* w_o    = (const float*)d_in[4];
    const float* w_qrot = (const float*)d_in[5];
    const float* w_krot = (const float*)d_in[6];
    float* out = (float*)d_out;

    const size_t M = 4096;
    __bf16* ws   = (__bf16*)d_ws;
    __bf16* xb   = ws;                        // 4096x2048
    __bf16* wcat = xb + M * 2048;             // 3648x2048 = [w_q|w_qrot|w_krot|w_dkv]
    __bf16* wqb  = wcat;
    __bf16* wqrb = wcat + (size_t)2048 * 2048;
    __bf16* wkrb = wqrb + (size_t)1024 * 2048;
    __bf16* wdkb = wkrb + (size_t)64 * 2048;
    __bf16* wukb = wcat + (size_t)QSTR * 2048; // 4096x512
    __bf16* wob  = wukb + (size_t)4096 * 512;  // 2048x2048
    __bf16* qcat = wob  + (size_t)2048 * 2048; // 4096x3648 (q|qrot|krot|dkv)
    __bf16* ukv  = qcat + M * QSTR;            // 4096x4096
    __bf16* ao   = ukv  + M * 4096;            // 4096x2048
    __bf16* vtt  = ao   + M * 2048;            // 1024 tiles x 128x64 (~16.8MB)

    dim3 blk(256);

    CastArgs ca;
    ca.s[0] = x;      ca.d[0] = xb;
    ca.s[1] = w_q;    ca.d[1] = wqb;
    ca.s[2] = w_qrot; ca.d[2] = wqrb;
    ca.s[3] = w_krot; ca.d[3] = wkrb;
    ca.s[4] = w_dkv;  ca.d[4] = wdkb;
    ca.s[5] = w_ukv;  ca.d[5] = wukb;
    ca.s[6] = w_o;    ca.d[6] = wob;
    ca.cum[0] = 0;
    ca.cum[1] = ca.cum[0] + 4096;
    ca.cum[2] = ca.cum[1] + 2048;
    ca.cum[3] = ca.cum[2] + 1024;
    ca.cum[4] = ca.cum[3] + 64;
    ca.cum[5] = ca.cum[4] + 512;
    ca.cum[6] = ca.cum[5] + 1024;
    ca.cum[7] = ca.cum[6] + 2048;
    cast_all<<<ca.cum[7], blk, 0, stream>>>(ca);

    gemm_bt_256<__bf16><<<dim3(15, 16), dim3(512), 0, stream>>>(
        xb, 2048, wcat, qcat, 4096, QSTR, 2048);
    gemm_bt_256<__bf16><<<dim3(16, 16), dim3(512), 0, stream>>>(
        qcat + 3136, QSTR, wukb, ukv, 4096, 4096, 512);

    rope_all<<<8704, blk, 0, stream>>>(qcat);
    prep_v<<<dim3(32, 32), blk, 0, stream>>>(ukv, vtt);

    flash_mfma<<<dim3(16, 32), dim3(256), 0, stream>>>(qcat, ukv, vtt, ao);

    gemm_bt_8ph<float><<<dim3(8, 32), dim3(512), 0, stream>>>(
        ao, 2048, wob, out, 4096, 2048, 2048);
}

// Round 12
// 351.924 us; speedup vs baseline: 1.0921x; 1.0085x over previous
//
#include <hip/hip_runtime.h>
#include <hip/hip_bf16.h>
#include <math.h>

#define T_SEQ 2048
#define QSTR  3648   // combined q|qrot|krot|dkv row stride

typedef __bf16 bf16x8 __attribute__((ext_vector_type(8)));
typedef float  f32x4  __attribute__((ext_vector_type(4)));
typedef float  f32x16 __attribute__((ext_vector_type(16)));
typedef unsigned int u32x4 __attribute__((ext_vector_type(4)));

#define GLOAD_LDS16(g, l) __builtin_amdgcn_global_load_lds( \
    (const __attribute__((address_space(1))) void*)(g),      \
    (__attribute__((address_space(3))) void*)(l), 16, 0, 0)

#define VMCNT(n) asm volatile("s_waitcnt vmcnt(" #n ")" ::: "memory")

static __device__ __forceinline__ unsigned cvtpk_bf16(float a, float b)
{
    unsigned r;
    asm("v_cvt_pk_bf16_f32 %0, %1, %2" : "=v"(r) : "v"(a), "v"(b));
    return r;
}

static __device__ __forceinline__ float fexp2(float x)
{
    float r;
    asm("v_exp_f32 %0, %1" : "=v"(r) : "v"(x));
    return r;
}

// ---------------- fused fp32 -> bf16 cast for all 7 buffers ----------------
struct CastArgs {
    const float* s[7];
    __bf16*      d[7];
    unsigned     cum[8];    // cumulative block counts (2048 elements per block)
};

__global__ __launch_bounds__(256) void cast_all(CastArgs a)
{
    const unsigned blk = blockIdx.x;
    int idx = 0;
    #pragma unroll
    for (int i = 1; i < 7; i++) if (blk >= a.cum[i]) idx = i;
    const unsigned local = blk - a.cum[idx];
    const float* src = a.s[idx];
    __bf16* dst = a.d[idx];
    const int i = (int)(local * 256 + threadIdx.x) * 8;
    float4 va = *reinterpret_cast<const float4*>(src + i);
    float4 vb = *reinterpret_cast<const float4*>(src + i + 4);
    bf16x8 f;
    f[0] = (__bf16)va.x; f[1] = (__bf16)va.y; f[2] = (__bf16)va.z; f[3] = (__bf16)va.w;
    f[4] = (__bf16)vb.x; f[5] = (__bf16)vb.y; f[6] = (__bf16)vb.z; f[7] = (__bf16)vb.w;
    *reinterpret_cast<bf16x8*>(dst + i) = f;
}

// ---------------- merged in-place RoPE (qrot + krot in one dispatch) --------
__global__ __launch_bounds__(256) void rope_all(__bf16* qcat)
{
    const unsigned blk = blockIdx.x;
    __bf16* buf;
    int shift, gid;
    if (blk < 8192) { buf = qcat + 2048; shift = 9; gid = blk * 256 + threadIdx.x; }
    else            { buf = qcat + 3072; shift = 5; gid = (blk - 8192) * 256 + threadIdx.x; }
    int row = gid >> shift;
    int rem = gid & ((1 << shift) - 1);
    int hb = rem >> 5, j = rem & 31;
    int t = row & (T_SEQ - 1);
    const float L2B = 0.4152410118609203f;      // log2(10000)/32
    float freq = exp2f(-L2B * (float)j);
    float sn, cs;
    __sincosf((float)t * freq, &sn, &cs);
    size_t base = (size_t)row * QSTR + hb * 64 + j;
    float v1 = (float)buf[base], v2 = (float)buf[base + 32];
    buf[base]      = (__bf16)(v1 * cs - v2 * sn);
    buf[base + 32] = (__bf16)(v2 * cs + v1 * sn);
}

// ---------------- V pre-transpose: vtt[bh][u][dv(128)][k(64)] XOR-swizzled ---
__global__ __launch_bounds__(256) void prep_v(const __bf16* __restrict__ ukv,
                                              __bf16* __restrict__ vtt)
{
    __shared__ __align__(16) __bf16 Ls[64 * 136];
    const int tid = threadIdx.x;
    const int u = blockIdx.x, bh = blockIdx.y;
    const int b = bh >> 4, h = bh & 15;
    const size_t base = (size_t)b * T_SEQ + u * 64;
    #pragma unroll
    for (int p = 0; p < 4; p++) {
        int c = tid + 256 * p;
        int k = c >> 4, dv8 = (c & 15) * 8;
        *reinterpret_cast<bf16x8*>(Ls + k * 136 + dv8) =
            *reinterpret_cast<const bf16x8*>(ukv + (base + k) * 4096 + h * 256 + 128 + dv8);
    }
    __syncthreads();
    #pragma unroll
    for (int p = 0; p < 4; p++) {
        int c = tid + 256 * p;
        int dv = c >> 3, kb = c & 7;
        bf16x8 f;
        #pragma unroll
        for (int i = 0; i < 8; i++) f[i] = Ls[(kb * 8 + i) * 136 + dv];
        *reinterpret_cast<bf16x8*>(vtt + (((size_t)bh * 32 + u) * 128 + dv) * 64
                                   + ((kb ^ (dv & 7)) << 3)) = f;
    }
}

// ---------------- 256x256 snake-phase counted-vmcnt GEMM (+XCD swizzle) -----
template <typename OutT>
__global__ __launch_bounds__(512, 2) void gemm_bt_256(const __bf16* __restrict__ A,
                                                      int lda,
                                                      const __bf16* __restrict__ B,
                                                      OutT* __restrict__ C,
                                                      int M, int N, int K)
{
    __shared__ __align__(16) __bf16 S[2 * 32768];   // 128KB
    const int tid  = threadIdx.x;
    const int lane = tid & 63;
    const int w    = tid >> 6;
    const int l15  = lane & 15, quad = lane >> 4;
    const int wm = w >> 2, wn = w & 3;
    const unsigned nwg = gridDim.x * gridDim.y;
    const unsigned fid = blockIdx.y * gridDim.x + blockIdx.x;
    const unsigned swz = (fid & 7) * (nwg >> 3) + (fid >> 3);
    const int m0 = (int)(swz / gridDim.x) * 256, n0 = (int)(swz % gridDim.x) * 256;
    const int NT = K >> 6;

    f32x4 acc[8][4] = {};
    bf16x8 af[4][2], bfr[2][2];

    auto stageA = [&](int T1, int h) {
        int d = T1 & 1;
        #pragma unroll
        for (int i = 0; i < 2; i++) {
            int c = i * 512 + tid;
            int lr = c >> 3, seg = c & 7;
            int g = ((lr >> 6) << 7) + h * 64 + (lr & 63);
            GLOAD_LDS16(A + (size_t)(m0 + g) * lda + T1 * 64 + ((seg ^ (lr & 7)) << 3),
                        S + d * 32768 + h * 8192 + c * 8);
        }
    };
    auto stageB = [&](int T1, int h) {
        int d = T1 & 1;
        #pragma unroll
        for (int i = 0; i < 2; i++) {
            int c = i * 512 + tid;
            int lr = c >> 3, seg = c & 7;
            int g = n0 + ((lr >> 5) << 6) + h * 32 + (lr & 31);
            if (g >= N) g = N - 1;
            GLOAD_LDS16(B + (size_t)g * K + T1 * 64 + ((seg ^ (lr & 7)) << 3),
                        S + d * 32768 + 16384 + h * 8192 + c * 8);
        }
    };

#define LOADA(d, mh) do {                                                      \
    const __bf16* Ah_ = S + (d) * 32768 + (mh) * 8192;                         \
    _Pragma("unroll")                                                          \
    for (int mi = 0; mi < 4; mi++) {                                           \
        int lr = wm * 64 + mi * 16 + l15;                                      \
        _Pragma("unroll")                                                      \
        for (int kk = 0; kk < 2; kk++)                                         \
            af[mi][kk] = *reinterpret_cast<const bf16x8*>(                     \
                Ah_ + lr * 64 + (((kk * 4 + quad) ^ (lr & 7)) << 3));          \
    }                                                                          \
} while (0)

#define LOADB(d, nh) do {                                                      \
    const __bf16* Bh_ = S + (d) * 32768 + 16384 + (nh) * 8192;                 \
    _Pragma("unroll")                                                          \
    for (int ni = 0; ni < 2; ni++) {                                           \
        int lr = wn * 32 + ni * 16 + l15;                                      \
        _Pragma("unroll")                                                      \
        for (int kk = 0; kk < 2; kk++)                                         \
            bfr[ni][kk] = *reinterpret_cast<const bf16x8*>(                    \
                Bh_ + lr * 64 + (((kk * 4 + quad) ^ (lr & 7)) << 3));          \
    }                                                                          \
} while (0)

#define SEAL() do {                                                            \
    __builtin_amdgcn_s_barrier();                                              \
    asm volatile("s_waitcnt lgkmcnt(0)" ::: "memory");                         \
    __builtin_amdgcn_sched_barrier(0);                                         \
} while (0)

#define MMA(mh, nh) do {                                                       \
    __builtin_amdgcn_s_setprio(1);                                             \
    _Pragma("unroll")                                                          \
    for (int mi = 0; mi < 4; mi++)                                             \
        _Pragma("unroll")                                                      \
        for (int ni = 0; ni < 2; ni++)                                         \
            _Pragma("unroll")                                                  \
            for (int kk = 0; kk < 2; kk++)                                     \
                acc[(mh) * 4 + mi][(nh) * 2 + ni] =                            \
                    __builtin_amdgcn_mfma_f32_16x16x32_bf16(                   \
                        af[mi][kk], bfr[ni][kk],                               \
                        acc[(mh) * 4 + mi][(nh) * 2 + ni], 0, 0, 0);           \
    __builtin_amdgcn_s_setprio(0);                                             \
} while (0)

    stageA(0, 0); stageB(0, 0); stageB(0, 1); stageA(0, 1);
    VMCNT(4);
    __builtin_amdgcn_s_barrier();

    for (int T = 0; T < NT - 1; T++) {
        const int d = T & 1;
        LOADA(d, 0); LOADB(d, 0); stageA(T + 1, 0); VMCNT(4); SEAL(); MMA(0, 0);
        LOADB(d, 1);              stageB(T + 1, 0); VMCNT(4); SEAL(); MMA(0, 1);
        LOADA(d, 1);              stageB(T + 1, 1);           SEAL(); MMA(1, 1);
        LOADB(d, 0);              stageA(T + 1, 1); VMCNT(4); SEAL(); MMA(1, 0);
    }
    {
        const int d = (NT - 1) & 1;
        LOADA(d, 0); LOADB(d, 0); VMCNT(2); SEAL(); MMA(0, 0);
        LOADB(d, 1);              VMCNT(0); SEAL(); MMA(0, 1);
        LOADA(d, 1);                        SEAL(); MMA(1, 1);
        LOADB(d, 0);                        SEAL(); MMA(1, 0);
    }
#undef LOADA
#undef LOADB
#undef SEAL
#undef MMA

    #pragma unroll
    for (int ai = 0; ai < 8; ai++) {
        #pragma unroll
        for (int bj = 0; bj < 4; bj++) {
            int col = n0 + wn * 64 + bj * 16 + l15;
            if (col < N) {
                #pragma unroll
                for (int r = 0; r < 4; r++) {
                    size_t row = m0 + wm * 128 + ai * 16 + quad * 4 + r;
                    C[row * (size_t)N + col] = (OutT)acc[ai][bj][r];
                }
            }
        }
    }
}

// ---------------- BM=128/BN=256 snake-phase GEMM (out-projection) -----------
// 96KB LDS (2 dbuf x {A 128x64 in 2 row-interleaved halves, B 256x64 in 2}),
// snake phase order (0,0)(0,1)(1,1)(1,0): phases 2-4 reload ONE operand (4
// ds_read per 8 MFMA). Counted-vmcnt by FIFO sim (issue +1/+2/+2/+1):
// prologue 3; phases 2/3/-/3; tail 1/0/-/-; never 0 mid-loop. +XCD swizzle.
template <typename OutT>
__global__ __launch_bounds__(512) void gemm_bt_sn128(const __bf16* __restrict__ A,
                                                     int lda,
                                                     const __bf16* __restrict__ B,
                                                     OutT* __restrict__ C,
                                                     int M, int N, int K)
{
    __shared__ __align__(16) __bf16 S[2 * 24576];   // 96KB
    const int tid  = threadIdx.x;
    const int lane = tid & 63;
    const int w    = tid >> 6;
    const int l15  = lane & 15, quad = lane >> 4;
    const int wm = w >> 2, wn = w & 3;
    const unsigned nwg = gridDim.x * gridDim.y;
    const unsigned fid = blockIdx.y * gridDim.x + blockIdx.x;
    const unsigned swz = (fid & 7) * (nwg >> 3) + (fid >> 3);
    const int m0 = (int)(swz / gridDim.x) * 128, n0 = (int)(swz % gridDim.x) * 256;
    const int NT = K >> 6;

    f32x4 acc[4][4] = {};
    bf16x8 af[2][2], bfr[2][2];

    const int lrA = tid >> 3, segA = tid & 7;
    auto stageA = [&](int T1, int h) {     // A-half h = rows {h*32..+31, 64+h*32..+31}
        int d = T1 & 1;
        int g = ((lrA >> 5) << 6) + h * 32 + (lrA & 31);
        GLOAD_LDS16(A + (size_t)(m0 + g) * lda + T1 * 64 + ((segA ^ (lrA & 7)) << 3),
                    S + d * 24576 + h * 4096 + tid * 8);
    };
    auto stageB = [&](int T1, int h) {
        int d = T1 & 1;
        #pragma unroll
        for (int i = 0; i < 2; i++) {
            int c = i * 512 + tid;
            int lr = c >> 3, seg = c & 7;
            int g = n0 + ((lr >> 5) << 6) + h * 32 + (lr & 31);
            if (g >= N) g = N - 1;
            GLOAD_LDS16(B + (size_t)g * K + T1 * 64 + ((seg ^ (lr & 7)) << 3),
                        S + d * 24576 + 8192 + h * 8192 + c * 8);
        }
    };

#define LOADAx(d, mh) do {                                                     \
    const __bf16* Ah_ = S + (d) * 24576 + (mh) * 4096;                         \
    _Pragma("unroll")                                                          \
    for (int mi = 0; mi < 2; mi++) {                                           \
        int lr = wm * 32 + mi * 16 + l15;                                      \
        _Pragma("unroll")                                                      \
        for (int kk = 0; kk < 2; kk++)                                         \
            af[mi][kk] = *reinterpret_cast<const bf16x8*>(                     \
                Ah_ + lr * 64 + (((kk * 4 + quad) ^ (lr & 7)) << 3));          \
    }                                                                          \
} while (0)

#define LOADBx(d, nh) do {                                                     \
    const __bf16* Bh_ = S + (d) * 24576 + 8192 + (nh) * 8192;                  \
    _Pragma("unroll")                                                          \
    for (int ni = 0; ni < 2; ni++) {                                           \
        int lr = wn * 32 + ni * 16 + l15;                                      \
        _Pragma("unroll")                                                      \
        for (int kk = 0; kk < 2; kk++)                                         \
            bfr[ni][kk] = *reinterpret_cast<const bf16x8*>(                    \
                Bh_ + lr * 64 + (((kk * 4 + quad) ^ (lr & 7)) << 3));          \
    }                                                                          \
} while (0)

#define SEALx() do {                                                           \
    __builtin_amdgcn_s_barrier();                                              \
    asm volatile("s_waitcnt lgkmcnt(0)" ::: "memory");                         \
    __builtin_amdgcn_sched_barrier(0);                                         \
} while (0)

#define MMAx(mh, nh) do {                                                      \
    __builtin_amdgcn_s_setprio(1);                                             \
    _Pragma("unroll")                                                          \
    for (int mi = 0; mi < 2; mi++)                                             \
        _Pragma("unroll")                                                      \
        for (int ni = 0; ni < 2; ni++)                                         \
            _Pragma("unroll")                                                  \
            for (int kk = 0; kk < 2; kk++)                                     \
                acc[(mh) * 2 + mi][(nh) * 2 + ni] =                            \
                    __builtin_amdgcn_mfma_f32_16x16x32_bf16(                   \
                        af[mi][kk], bfr[ni][kk],                               \
                        acc[(mh) * 2 + mi][(nh) * 2 + ni], 0, 0, 0);           \
    __builtin_amdgcn_s_setprio(0);                                             \
} while (0)

    stageA(0, 0); stageB(0, 0); stageB(0, 1); stageA(0, 1);   // 6 loads
    VMCNT(3);                   // A0,B0x2 landed; [B1x2,A1] in flight
    __builtin_amdgcn_s_barrier();

    for (int T = 0; T < NT - 1; T++) {
        const int d = T & 1;
        LOADAx(d, 0); LOADBx(d, 0); stageA(T + 1, 0); VMCNT(2); SEALx(); MMAx(0, 0);
        LOADBx(d, 1);               stageB(T + 1, 0); VMCNT(3); SEALx(); MMAx(0, 1);
        LOADAx(d, 1);               stageB(T + 1, 1);           SEALx(); MMAx(1, 1);
        LOADBx(d, 0);               stageA(T + 1, 1); VMCNT(3); SEALx(); MMAx(1, 0);
    }
    {   // tail: entering with [B1x2,A1] in flight
        const int d = (NT - 1) & 1;
        LOADAx(d, 0); LOADBx(d, 0); VMCNT(1); SEALx(); MMAx(0, 0);
        LOADBx(d, 1);               VMCNT(0); SEALx(); MMAx(0, 1);
        LOADAx(d, 1);                         SEALx(); MMAx(1, 1);
        LOADBx(d, 0);                         SEALx(); MMAx(1, 0);
    }
#undef LOADAx
#undef LOADBx
#undef SEALx
#undef MMAx

    #pragma unroll
    for (int ai = 0; ai < 4; ai++) {
        #pragma unroll
        for (int bj = 0; bj < 4; bj++) {
            const int mh = ai >> 1, mi = ai & 1;
            const int nh = bj >> 1, ni = bj & 1;
            const int lrB = wn * 32 + ni * 16 + l15;
            int col = n0 + ((lrB >> 5) << 6) + nh * 32 + (lrB & 31);
            if (col < N) {
                #pragma unroll
                for (int r = 0; r < 4; r++) {
                    size_t row = m0 + wm * 64 + mh * 32 + mi * 16 + quad * 4 + r;
                    C[row * (size_t)N + col] = (OutT)acc[ai][bj][r];
                }
            }
        }
    }
}

// ---------------- MFMA flash attention v2.1 (R9-verified, 91.7us) -----------
__global__ __launch_bounds__(256, 2) void flash_mfma(
    const __bf16* __restrict__ qcat, const __bf16* __restrict__ ukv,
    const __bf16* __restrict__ vtt, __bf16* __restrict__ obuf)
{
    __shared__ __align__(16) __bf16 LDS[40960];  // KsN 2x8192 | KsR 2x4096 | Vt 2x8192

    const int tid  = threadIdx.x;
    const int w    = tid >> 6;
    const int lane = tid & 63;
    const int l31  = lane & 31;
    const int lh   = lane >> 5;
    const int l15  = lane & 15;
    const int quad = lane >> 4;
    const int gx = blockIdx.x, gy = blockIdx.y;
    int bh, qi;
    if (gy < 16) { bh = gy * 2;            qi = gx; }
    else         { bh = (gy - 16) * 2 + 1; qi = 15 - gx; }
    const int b = bh >> 4, h = bh & 15;
    const int q0 = qi * 128;
    const float SC2 = 0.10411754900f;   // (1/sqrt(192)) * log2(e)
    const size_t urow = (size_t)b * T_SEQ;

    const int q = q0 + 32 * w + l31;
    bf16x8 qf[12];
    {
        const __bf16* qrow = qcat + (urow + q) * QSTR + h * 128;
        #pragma unroll
        for (int dk = 0; dk < 8; dk++)
            qf[dk] = *reinterpret_cast<const bf16x8*>(qrow + 16 * dk + 8 * lh);
        const __bf16* qrr = qcat + (urow + q) * QSTR + 2048 + h * 64;
        #pragma unroll
        for (int dk = 0; dk < 4; dk++)
            qf[8 + dk] = *reinterpret_cast<const bf16x8*>(qrr + 16 * dk + 8 * lh);
    }

    f32x16 o[4] = {};
    float m_i = -INFINITY, l_i = 0.f;

    const int nunits = 2 * qi + 2;

    auto stage = [&](int x) {           // 10 global_load_lds per thread
        const int d1 = x & 1;
        const size_t roff = urow + (size_t)64 * x;
        #pragma unroll
        for (int p = 0; p < 4; p++) {
            int c = tid + 256 * p;
            int row = c >> 4, seg = c & 15;
            GLOAD_LDS16(ukv + (roff + row) * 4096 + h * 256 + ((seg ^ (row & 7)) << 3),
                        LDS + d1 * 8192 + c * 8);
        }
        #pragma unroll
        for (int p = 0; p < 2; p++) {
            int c = tid + 256 * p;
            int row = c >> 3, seg = c & 7;
            GLOAD_LDS16(qcat + (roff + row) * QSTR + 3072 + ((seg ^ (row & 7)) << 3),
                        LDS + 16384 + d1 * 4096 + c * 8);
        }
        const __bf16* vsrc = vtt + ((size_t)bh * 32 + x) * 8192;
        #pragma unroll
        for (int p = 0; p < 4; p++) {
            int c = tid + 256 * p;
            GLOAD_LDS16(vsrc + c * 8, LDS + 24576 + d1 * 8192 + c * 8);
        }
    };

    stage(0);
    VMCNT(0);
    __builtin_amdgcn_s_barrier();

    for (int u = 0; u < nunits; u++) {
        if (u + 1 < nunits) { stage(u + 1); VMCNT(10); }
        else                { VMCNT(0); }
        __builtin_amdgcn_s_barrier();
        __builtin_amdgcn_sched_barrier(0);

        const int d1 = u & 1;
        const __bf16* KN = LDS + d1 * 8192;
        const __bf16* KR = LDS + 16384 + d1 * 4096;
        const __bf16* VT = LDS + 24576 + d1 * 8192;
        const int key = l31 & 7;

        f32x16 s2[2] = {};
        __builtin_amdgcn_s_setprio(1);
        #pragma unroll
        for (int t = 0; t < 2; t++) {
            const __bf16* kn = KN + (32 * t + l31) * 128;
            const __bf16* kr = KR + (32 * t + l31) * 64;
            #pragma unroll
            for (int dk = 0; dk < 8; dk++) {
                bf16x8 kf = *reinterpret_cast<const bf16x8*>(kn + (((2 * dk + lh) ^ key) << 3));
                s2[t] = __builtin_amdgcn_mfma_f32_32x32x16_bf16(kf, qf[dk], s2[t], 0, 0, 0);
            }
            #pragma unroll
            for (int dk = 0; dk < 4; dk++) {
                bf16x8 kf = *reinterpret_cast<const bf16x8*>(kr + (((2 * dk + lh) ^ key) << 3));
                s2[t] = __builtin_amdgcn_mfma_f32_32x32x16_bf16(kf, qf[8 + dk], s2[t], 0, 0, 0);
            }
        }
        __builtin_amdgcn_s_setprio(0);

        const int k0 = 64 * u;
        const bool domask = (u + 2 >= nunits);
        float rmax = -INFINITY;
        #pragma unroll
        for (int t = 0; t < 2; t++)
            #pragma unroll
            for (int g = 0; g < 16; g++) {
                float v = s2[t][g] * SC2;        // log2-domain scores
                if (domask) {
                    int kg = k0 + 32 * t + (g & 3) + 8 * (g >> 2) + 4 * lh;
                    if (kg > q) v = -INFINITY;
                }
                s2[t][g] = v;
                rmax = fmaxf(rmax, v);
            }
        rmax = fmaxf(rmax, __shfl_xor(rmax, 32, 64));
        if (__any(rmax > m_i + 8.0f)) {          // defer-max (T13)
            const float mnew  = fmaxf(m_i, rmax);
            const float alpha = fexp2(m_i - mnew);
            m_i = mnew;
            l_i *= alpha;
            #pragma unroll
            for (int dt = 0; dt < 4; dt++) o[dt] *= alpha;
        }
        float part = 0.f;
        #pragma unroll
        for (int t = 0; t < 2; t++)
            #pragma unroll
            for (int g = 0; g < 16; g++) {
                float pv = fexp2(s2[t][g] - m_i);   // bounded by 2^8
                s2[t][g] = pv;
                part += pv;
            }
        l_i += part;

        __builtin_amdgcn_s_setprio(1);
        #pragma unroll
        for (int t = 0; t < 2; t++) {
            unsigned Ap[4], Bp[4];
            #pragma unroll
            for (int g = 0; g < 4; g++) {
                Ap[g] = cvtpk_bf16(s2[t][4 * g],     s2[t][4 * g + 1]);
                Bp[g] = cvtpk_bf16(s2[t][4 * g + 2], s2[t][4 * g + 3]);
            }
            #pragma unroll
            for (int sub = 0; sub < 2; sub++) {
                unsigned xA = lh ? Ap[2 * sub] : Ap[2 * sub + 1];
                unsigned xB = lh ? Bp[2 * sub] : Bp[2 * sub + 1];
                unsigned rA = __shfl_xor(xA, 32, 64);
                unsigned rB = __shfl_xor(xB, 32, 64);
                u32x4 uv;
                uv[0] = lh ? rA : Ap[2 * sub];
                uv[1] = lh ? rB : Bp[2 * sub];
                uv[2] = lh ? Ap[2 * sub + 1] : rA;
                uv[3] = lh ? Bp[2 * sub + 1] : rB;
                bf16x8 pf = __builtin_bit_cast(bf16x8, uv);
                const int s = 2 * t + sub;
                #pragma unroll
                for (int dt = 0; dt < 4; dt++) {
                    bf16x8 vf = *reinterpret_cast<const bf16x8*>(
                        VT + (32 * dt + l31) * 64 + (((2 * s + lh) ^ key) << 3));
                    o[dt] = __builtin_amdgcn_mfma_f32_32x32x16_bf16(vf, pf, o[dt], 0, 0, 0);
                }
            }
        }
        __builtin_amdgcn_s_setprio(0);

        __builtin_amdgcn_sched_barrier(0);
        __builtin_amdgcn_s_barrier();
    }

    const float linv = 1.0f / (l_i + __shfl_xor(l_i, 32, 64));
    float* Os = reinterpret_cast<float*>(LDS);     // [128 q][132 d]
    #pragma unroll
    for (int dt = 0; dt < 4; dt++)
        #pragma unroll
        for (int g = 0; g < 16; g++) {
            int d = 32 * dt + (g & 3) + 8 * (g >> 2) + 4 * lh;
            Os[(32 * w + l31) * 132 + d] = o[dt][g] * linv;
        }
    asm volatile("s_waitcnt lgkmcnt(0)" ::: "memory");
    __builtin_amdgcn_sched_barrier(0);
    #pragma unroll
    for (int p = 0; p < 8; p++) {
        int row = 32 * w + 4 * p + quad;
        float4 a4 = *reinterpret_cast<const float4*>(Os + row * 132 + 8 * l15);
        float4 c2 = *reinterpret_cast<const float4*>(Os + row * 132 + 8 * l15 + 4);
        bf16x8 f;
        f[0] = (__bf16)a4.x; f[1] = (__bf16)a4.y; f[2] = (__bf16)a4.z; f[3] = (__bf16)a4.w;
        f[4] = (__bf16)c2.x; f[5] = (__bf16)c2.y; f[6] = (__bf16)c2.z; f[7] = (__bf16)c2.w;
        *reinterpret_cast<bf16x8*>(obuf + (urow + q0 + row) * 2048 + h * 128 + 8 * l15) = f;
    }
}

extern "C" void kernel_launch(void* const* d_in, const int* in_sizes, int n_in,
                              void* d_out, int out_size, void* d_ws, size_t ws_size,
                              hipStream_t stream)
{
    const float* x      = (const float*)d_in[0];
    const float* w_q    = (const float*)d_in[1];
    const float* w_dkv  = (const float*)d_in[2];
    const float* w_ukv  = (const float*)d_in[3];
    const float* w_o    = (const float*)d_in[4];
    const float* w_qrot = (const float*)d_in[5];
    const float* w_krot = (const float*)d_in[6];
    float* out = (float*)d_out;

    const size_t M = 4096;
    __bf16* ws   = (__bf16*)d_ws;
    __bf16* xb   = ws;                        // 4096x2048
    __bf16* wcat = xb + M * 2048;             // 3648x2048 = [w_q|w_qrot|w_krot|w_dkv]
    __bf16* wqb  = wcat;
    __bf16* wqrb = wcat + (size_t)2048 * 2048;
    __bf16* wkrb = wqrb + (size_t)1024 * 2048;
    __bf16* wdkb = wkrb + (size_t)64 * 2048;
    __bf16* wukb = wcat + (size_t)QSTR * 2048; // 4096x512
    __bf16* wob  = wukb + (size_t)4096 * 512;  // 2048x2048
    __bf16* qcat = wob  + (size_t)2048 * 2048; // 4096x3648 (q|qrot|krot|dkv)
    __bf16* ukv  = qcat + M * QSTR;            // 4096x4096
    __bf16* ao   = ukv  + M * 4096;            // 4096x2048
    __bf16* vtt  = ao   + M * 2048;            // 1024 tiles x 128x64 (~16.8MB)

    dim3 blk(256);

    CastArgs ca;
    ca.s[0] = x;      ca.d[0] = xb;
    ca.s[1] = w_q;    ca.d[1] = wqb;
    ca.s[2] = w_qrot; ca.d[2] = wqrb;
    ca.s[3] = w_krot; ca.d[3] = wkrb;
    ca.s[4] = w_dkv;  ca.d[4] = wdkb;
    ca.s[5] = w_ukv;  ca.d[5] = wukb;
    ca.s[6] = w_o;    ca.d[6] = wob;
    ca.cum[0] = 0;
    ca.cum[1] = ca.cum[0] + 4096;
    ca.cum[2] = ca.cum[1] + 2048;
    ca.cum[3] = ca.cum[2] + 1024;
    ca.cum[4] = ca.cum[3] + 64;
    ca.cum[5] = ca.cum[4] + 512;
    ca.cum[6] = ca.cum[5] + 1024;
    ca.cum[7] = ca.cum[6] + 2048;
    cast_all<<<ca.cum[7], blk, 0, stream>>>(ca);

    gemm_bt_256<__bf16><<<dim3(15, 16), dim3(512), 0, stream>>>(
        xb, 2048, wcat, qcat, 4096, QSTR, 2048);
    gemm_bt_256<__bf16><<<dim3(16, 16), dim3(512), 0, stream>>>(
        qcat + 3136, QSTR, wukb, ukv, 4096, 4096, 512);

    rope_all<<<8704, blk, 0, stream>>>(qcat);
    prep_v<<<dim3(32, 32), blk, 0, stream>>>(ukv, vtt);

    flash_mfma<<<dim3(16, 32), dim3(256), 0, stream>>>(qcat, ukv, vtt, ao);

    gemm_bt_sn128<float><<<dim3(8, 32), dim3(512), 0, stream>>>(
        ao, 2048, wob, out, 4096, 2048, 2048);
}